// Round 4
// baseline (723.686 us; speedup 1.0000x reference)
//
#include <hip/hip_runtime.h>
#include <hip/hip_bf16.h>

// GroupedQueryAttention: B=2,S=2048,D=2048,H=16,G=4,HD=128, causal, rmsnorm+rope.
// Inputs fp32 (round-1 NaN proves it); OUTPUT fp32 (round-2/3 3.765625 signature:
// half-written fp32 buffer). Internal compute bf16 MFMA / fp32 accumulate.
// ws (44 MB): qb[B,H,S,HD] | kb[B,G,S,HD] | vb[B,G,S,HD] | vtb[B,G,HD,S] | ctx[B,S,H*HD] (bf16)

typedef __bf16 bf16_t;
using bf16x8 = __attribute__((ext_vector_type(8))) __bf16;
using f32x4  = __attribute__((ext_vector_type(4))) float;

// ---------- shared 128x128-tile GEMM mainloop: C = A[M,K] * B[N,K]^T ----------
// LDS rows padded to 72 elements (144 B): b128 frag reads land 2-way (free).
// Explicit staging: global vector load (+cvt if fp32) -> ds_write_b128.
template <bool A_F32, bool B_F32>
__device__ __forceinline__ void gemm_tile(const void* __restrict__ AP,
                                          const void* __restrict__ BP, int K,
                                          int m0, int n0, bf16_t* As, bf16_t* Bs,
                                          f32x4 acc[4][4]) {
  const int tid = threadIdx.x;
  const int lane = tid & 63, w = tid >> 6;
  const int quad = lane >> 4, l16 = lane & 15;
  const int wm = (w >> 1) * 64, wn = (w & 1) * 64;
  const int nkt = K >> 6;
  for (int kt = 0; kt < nkt; ++kt) {
#pragma unroll
    for (int i = 0; i < 4; ++i) {
      int s = i * 256 + tid;
      int row = s >> 3, ch = s & 7;
      bf16x8 av, bv;
      if (A_F32) {
        const float* g = (const float*)AP + (size_t)(m0 + row) * K + kt * 64 + ch * 8;
        f32x4 u0 = *(const f32x4*)g;
        f32x4 u1 = *(const f32x4*)(g + 4);
        av[0] = (bf16_t)u0[0]; av[1] = (bf16_t)u0[1]; av[2] = (bf16_t)u0[2]; av[3] = (bf16_t)u0[3];
        av[4] = (bf16_t)u1[0]; av[5] = (bf16_t)u1[1]; av[6] = (bf16_t)u1[2]; av[7] = (bf16_t)u1[3];
      } else {
        av = *(const bf16x8*)((const bf16_t*)AP + (size_t)(m0 + row) * K + kt * 64 + ch * 8);
      }
      if (B_F32) {
        const float* g = (const float*)BP + (size_t)(n0 + row) * K + kt * 64 + ch * 8;
        f32x4 u0 = *(const f32x4*)g;
        f32x4 u1 = *(const f32x4*)(g + 4);
        bv[0] = (bf16_t)u0[0]; bv[1] = (bf16_t)u0[1]; bv[2] = (bf16_t)u0[2]; bv[3] = (bf16_t)u0[3];
        bv[4] = (bf16_t)u1[0]; bv[5] = (bf16_t)u1[1]; bv[6] = (bf16_t)u1[2]; bv[7] = (bf16_t)u1[3];
      } else {
        bv = *(const bf16x8*)((const bf16_t*)BP + (size_t)(n0 + row) * K + kt * 64 + ch * 8);
      }
      *(bf16x8*)(As + row * 72 + ch * 8) = av;
      *(bf16x8*)(Bs + row * 72 + ch * 8) = bv;
    }
    __syncthreads();
#pragma unroll
    for (int kk = 0; kk < 2; ++kk) {
      bf16x8 af[4], bfv[4];
#pragma unroll
      for (int i = 0; i < 4; ++i) {
        af[i]  = *(const bf16x8*)(As + (wm + i * 16 + l16) * 72 + kk * 32 + quad * 8);
        bfv[i] = *(const bf16x8*)(Bs + (wn + i * 16 + l16) * 72 + kk * 32 + quad * 8);
      }
#pragma unroll
      for (int im = 0; im < 4; ++im)
#pragma unroll
        for (int in_ = 0; in_ < 4; ++in_)
          acc[im][in_] = __builtin_amdgcn_mfma_f32_16x16x32_bf16(
              af[im], bfv[in_], acc[im][in_], 0, 0, 0);
    }
    __syncthreads();
  }
}

// ---------- fused QKV projection; writes head-major [B,Hn,S,HD] bf16 ----------
__global__ __launch_bounds__(256) void qkv_gemm(
    const float* __restrict__ x, const float* __restrict__ Wq,
    const float* __restrict__ Wk, const float* __restrict__ Wv,
    bf16_t* __restrict__ qo, bf16_t* __restrict__ ko, bf16_t* __restrict__ vo) {
  __shared__ __align__(16) bf16_t As[128 * 72];
  __shared__ __align__(16) bf16_t Bs[128 * 72];
  const int n0g = blockIdx.x * 128;  // 0..3071 over [q|k|v]
  const int m0 = blockIdx.y * 128;
  const float* B;
  bf16_t* O;
  int Hn, n0;
  if (n0g < 2048)      { B = Wq; O = qo; Hn = 16; n0 = n0g; }
  else if (n0g < 2560) { B = Wk; O = ko; Hn = 4;  n0 = n0g - 2048; }
  else                 { B = Wv; O = vo; Hn = 4;  n0 = n0g - 2560; }
  f32x4 acc[4][4] = {};
  gemm_tile<true, true>(x, B, 2048, m0, n0, As, Bs, acc);
  const int lane = threadIdx.x & 63, w = threadIdx.x >> 6;
  const int quad = lane >> 4, l16 = lane & 15;
  const int wm = (w >> 1) * 64, wn = (w & 1) * 64;
#pragma unroll
  for (int im = 0; im < 4; ++im)
#pragma unroll
    for (int in_ = 0; in_ < 4; ++in_)
#pragma unroll
      for (int r = 0; r < 4; ++r) {
        int gr = m0 + wm + im * 16 + quad * 4 + r;   // row = b*S+s
        int gc = n0 + wn + in_ * 16 + l16;           // col = h*HD+d
        int bb = gr >> 11, ss = gr & 2047, hh = gc >> 7, dd = gc & 127;
        O[(((size_t)bb * Hn + hh) * 2048 + ss) * 128 + dd] = (bf16_t)acc[im][in_][r];
      }
}

// ---------- output projection: out[B*S,2048] = ctx(bf16) * Wo(fp32)^T, fp32 out
__global__ __launch_bounds__(256) void out_gemm(const bf16_t* __restrict__ ctx,
                                                const float* __restrict__ Wo,
                                                float* __restrict__ out) {
  __shared__ __align__(16) bf16_t As[128 * 72];
  __shared__ __align__(16) bf16_t Bs[128 * 72];
  const int n0 = blockIdx.x * 128, m0 = blockIdx.y * 128;
  f32x4 acc[4][4] = {};
  gemm_tile<false, true>(ctx, Wo, 2048, m0, n0, As, Bs, acc);
  const int lane = threadIdx.x & 63, w = threadIdx.x >> 6;
  const int quad = lane >> 4, l16 = lane & 15;
  const int wm = (w >> 1) * 64, wn = (w & 1) * 64;
#pragma unroll
  for (int im = 0; im < 4; ++im)
#pragma unroll
    for (int in_ = 0; in_ < 4; ++in_)
#pragma unroll
      for (int r = 0; r < 4; ++r) {
        int gr = m0 + wm + im * 16 + quad * 4 + r;
        int gc = n0 + wn + in_ * 16 + l16;
        out[(size_t)gr * 2048 + gc] = acc[im][in_][r];
      }
}

// ---------- RMSNorm + RoPE (in place on bf16 scratch), one wave per row ------
__global__ __launch_bounds__(256) void rmsnorm_rope(bf16_t* __restrict__ x,
    const float* __restrict__ wgt, const float* __restrict__ cs,
    const float* __restrict__ sn, float outscale) {
  const int row = blockIdx.x * 4 + (threadIdx.x >> 6);
  const int lane = threadIdx.x & 63;
  const int pos = row & 2047;  // S=2048
  bf16_t* p = x + (size_t)row * 128;
  float v1 = (float)p[lane];
  float v2 = (float)p[lane + 64];
  float ss = v1 * v1 + v2 * v2;
#pragma unroll
  for (int m = 32; m; m >>= 1) ss += __shfl_xor(ss, m);
  float rr = rsqrtf(ss * (1.0f / 128.0f) + 1e-6f);
  float n1 = v1 * rr * wgt[lane];
  float n2 = v2 * rr * wgt[lane + 64];
  float c1 = cs[pos * 128 + lane],      s1 = sn[pos * 128 + lane];
  float c2 = cs[pos * 128 + lane + 64], s2 = sn[pos * 128 + lane + 64];
  p[lane]      = (bf16_t)((n1 * c1 - n2 * s1) * outscale);
  p[lane + 64] = (bf16_t)((n2 * c2 + n1 * s2) * outscale);
}

// ---------- V transpose: [BG,S,HD] -> [BG,HD,S] so PV B-frags are k-contig ---
__global__ __launch_bounds__(256) void vtrans(const bf16_t* __restrict__ v,
                                              bf16_t* __restrict__ vt) {
  __shared__ bf16_t t[64][72];
  const int bg = blockIdx.z, t0 = blockIdx.x * 64, d0 = blockIdx.y * 64;
  const int tid = threadIdx.x;
  const int r = tid >> 3, c = (tid & 7) * 8;
  const bf16_t* src = v + ((size_t)bg * 2048 + t0) * 128 + d0;
#pragma unroll
  for (int it = 0; it < 2; ++it) {
    uint4 val = *(const uint4*)(src + (size_t)(r + it * 32) * 128 + c);
    *(uint4*)&t[r + it * 32][c] = val;
  }
  __syncthreads();
#pragma unroll
  for (int it = 0; it < 2; ++it) {
    int d = r + it * 32;
    bf16_t tmp[8];
#pragma unroll
    for (int j = 0; j < 8; ++j) tmp[j] = t[c + j][d];
    *(uint4*)(vt + ((size_t)bg * 128 + d0 + d) * 2048 + t0 + c) = *(uint4*)tmp;
  }
}

// ---------- flash attention: 128 q-rows/block, K-tile=128, online softmax ----
// Unpadded 128-elem LDS rows (identity-copy staging). P overlays Klds.
__global__ __launch_bounds__(256) void attn_kernel(const bf16_t* __restrict__ q,
    const bf16_t* __restrict__ k, const bf16_t* __restrict__ vt,
    bf16_t* __restrict__ ctx) {
  __shared__ __align__(16) bf16_t Klds[128 * 128];
  __shared__ __align__(16) bf16_t Vlds[128 * 128];
  const int qt = blockIdx.x, h = blockIdx.y, b = blockIdx.z;
  const int g = h >> 2;  // GS = 4
  const int tid = threadIdx.x, w = tid >> 6, lane = tid & 63;
  const int quad = lane >> 4, l16 = lane & 15;
  const bf16_t* qp = q + (((size_t)b * 16 + h) * 2048 + (size_t)qt * 128) * 128;
  const bf16_t* kp = k + ((size_t)b * 4 + g) * 2048 * 128;
  const bf16_t* vtp = vt + ((size_t)b * 4 + g) * 128 * 2048;

  // Q A-fragments straight from global (k-contiguous 16B per lane)
  bf16x8 qf[2][4];
#pragma unroll
  for (int mt = 0; mt < 2; ++mt)
#pragma unroll
    for (int kk = 0; kk < 4; ++kk)
      qf[mt][kk] = *(const bf16x8*)(qp + (size_t)(w * 32 + mt * 16 + l16) * 128 +
                                    kk * 32 + quad * 8);

  f32x4 oacc[2][8] = {};
  float mrun[2][4], lrun[2][4];
#pragma unroll
  for (int mt = 0; mt < 2; ++mt)
#pragma unroll
    for (int r = 0; r < 4; ++r) { mrun[mt][r] = -1e30f; lrun[mt][r] = 0.f; }

  for (int kt = 0; kt <= qt; ++kt) {
    const bf16_t* ksrc = kp + (size_t)kt * 128 * 128;
    const bf16_t* vsrc = vtp + kt * 128;
#pragma unroll
    for (int i = 0; i < 8; ++i) {
      int s = i * 256 + tid;           // 0..2047 : 16B chunk index
      int row = s >> 4, ch = s & 15;
      *(bf16x8*)(Klds + s * 8) = *(const bf16x8*)(ksrc + s * 8);  // identity copy
      *(bf16x8*)(Vlds + s * 8) =
          *(const bf16x8*)(vsrc + (size_t)row * 2048 + ch * 8);
    }
    __syncthreads();

    // S = Q * K^T  (32 q-rows per wave)
    f32x4 sacc[2][8] = {};
#pragma unroll
    for (int kk = 0; kk < 4; ++kk)
#pragma unroll
      for (int nt = 0; nt < 8; ++nt) {
        bf16x8 kf = *(const bf16x8*)(Klds + (nt * 16 + l16) * 128 + kk * 32 + quad * 8);
#pragma unroll
        for (int mt = 0; mt < 2; ++mt)
          sacc[mt][nt] = __builtin_amdgcn_mfma_f32_16x16x32_bf16(
              qf[mt][kk], kf, sacc[mt][nt], 0, 0, 0);
      }

    if (kt == qt) {  // causal mask on diagonal tile (local positions)
#pragma unroll
      for (int mt = 0; mt < 2; ++mt) {
        int qrow = w * 32 + mt * 16 + quad * 4;
#pragma unroll
        for (int nt = 0; nt < 8; ++nt) {
          int kcol = nt * 16 + l16;
#pragma unroll
          for (int r = 0; r < 4; ++r)
            if (kcol > qrow + r) sacc[mt][nt][r] = -1e30f;
        }
      }
    }

    // online softmax: a C-tile row lives in the 16 lanes sharing `quad`
#pragma unroll
    for (int mt = 0; mt < 2; ++mt)
#pragma unroll
      for (int r = 0; r < 4; ++r) {
        float tm = sacc[mt][0][r];
#pragma unroll
        for (int nt = 1; nt < 8; ++nt) tm = fmaxf(tm, sacc[mt][nt][r]);
        tm = fmaxf(tm, __shfl_xor(tm, 1));
        tm = fmaxf(tm, __shfl_xor(tm, 2));
        tm = fmaxf(tm, __shfl_xor(tm, 4));
        tm = fmaxf(tm, __shfl_xor(tm, 8));
        float mn = fmaxf(mrun[mt][r], tm);
        float al = exp2f((mrun[mt][r] - mn) * 1.44269504f);
        mrun[mt][r] = mn;
        float rs = 0.f;
#pragma unroll
        for (int nt = 0; nt < 8; ++nt) {
          float pv = exp2f((sacc[mt][nt][r] - mn) * 1.44269504f);
          sacc[mt][nt][r] = pv;
          rs += pv;
        }
        rs += __shfl_xor(rs, 1);
        rs += __shfl_xor(rs, 2);
        rs += __shfl_xor(rs, 4);
        rs += __shfl_xor(rs, 8);
        lrun[mt][r] = lrun[mt][r] * al + rs;
#pragma unroll
        for (int nd = 0; nd < 8; ++nd) oacc[mt][nd][r] *= al;
      }

    __syncthreads();  // all waves done reading K before P overlays it

    // write P (C-layout scatter, plain row-major into Klds region)
#pragma unroll
    for (int mt = 0; mt < 2; ++mt)
#pragma unroll
      for (int nt = 0; nt < 8; ++nt)
#pragma unroll
        for (int r = 0; r < 4; ++r) {
          int prow = w * 32 + mt * 16 + quad * 4 + r;
          int pcol = nt * 16 + l16;
          Klds[prow * 128 + pcol] = (bf16_t)sacc[mt][nt][r];
        }
    __syncthreads();

    // O += P * V   (A = P from LDS, B = V^T tile, k-contiguous)
#pragma unroll
    for (int kkp = 0; kkp < 4; ++kkp) {
      bf16x8 pf[2];
#pragma unroll
      for (int mt = 0; mt < 2; ++mt)
        pf[mt] = *(const bf16x8*)(Klds + (w * 32 + mt * 16 + l16) * 128 +
                                  kkp * 32 + quad * 8);
#pragma unroll
      for (int nd = 0; nd < 8; ++nd) {
        bf16x8 vf = *(const bf16x8*)(Vlds + (nd * 16 + l16) * 128 + kkp * 32 + quad * 8);
#pragma unroll
        for (int mt = 0; mt < 2; ++mt)
          oacc[mt][nd] = __builtin_amdgcn_mfma_f32_16x16x32_bf16(
              pf[mt], vf, oacc[mt][nd], 0, 0, 0);
      }
    }
    __syncthreads();  // all reads done before next staging overwrites tiles
  }

  // epilogue: ctx[b][pos][h][d] = O / l
#pragma unroll
  for (int mt = 0; mt < 2; ++mt)
#pragma unroll
    for (int r = 0; r < 4; ++r) {
      float inv = 1.f / lrun[mt][r];
      int pos = qt * 128 + w * 32 + mt * 16 + quad * 4 + r;
      size_t base = (((size_t)b * 2048 + pos) * 16 + h) * 128;
#pragma unroll
      for (int nd = 0; nd < 8; ++nd)
        ctx[base + nd * 16 + l16] = (bf16_t)(oacc[mt][nd][r] * inv);
    }
}

extern "C" void kernel_launch(void* const* d_in, const int* in_sizes, int n_in,
                              void* d_out, int out_size, void* d_ws, size_t ws_size,
                              hipStream_t stream) {
  (void)in_sizes; (void)n_in; (void)out_size; (void)ws_size;
  const float* x    = (const float*)d_in[0];
  // d_in[1] = mask (causal, structural -> unused)
  const float* cosp = (const float*)d_in[2];
  const float* sinp = (const float*)d_in[3];
  const float* Wq   = (const float*)d_in[4];
  const float* Wk   = (const float*)d_in[5];
  const float* Wv   = (const float*)d_in[6];
  const float* Wo   = (const float*)d_in[7];
  const float* qnw  = (const float*)d_in[8];
  const float* knw  = (const float*)d_in[9];
  float* out = (float*)d_out;

  char* ws = (char*)d_ws;
  bf16_t* qb  = (bf16_t*)(ws);               // 16777216 B
  bf16_t* kb  = (bf16_t*)(ws + 16777216);    //  4194304 B
  bf16_t* vb  = (bf16_t*)(ws + 20971520);    //  4194304 B
  bf16_t* vtb = (bf16_t*)(ws + 25165824);    //  4194304 B
  bf16_t* ctx = (bf16_t*)(ws + 29360128);    // 16777216 B  (total 46137344 B)

  qkv_gemm<<<dim3(24, 32), 256, 0, stream>>>(x, Wq, Wk, Wv, qb, kb, vb);
  rmsnorm_rope<<<16384, 256, 0, stream>>>(qb, qnw, cosp, sinp, 0.08838834764831845f);
  rmsnorm_rope<<<4096, 256, 0, stream>>>(kb, knw, cosp, sinp, 1.0f);
  vtrans<<<dim3(32, 2, 8), 256, 0, stream>>>(vb, vtb);
  attn_kernel<<<dim3(16, 16, 2), 256, 0, stream>>>(qb, kb, vtb, ctx);
  out_gemm<<<dim3(16, 32), 256, 0, stream>>>(ctx, Wo, out);
}

// Round 5
// 578.713 us; speedup vs baseline: 1.2505x; 1.2505x over previous
//
#include <hip/hip_runtime.h>
#include <hip/hip_bf16.h>

// GroupedQueryAttention: B=2,S=2048,D=2048,H=16,G=4,HD=128, causal, rmsnorm+rope.
// Inputs fp32; OUTPUT fp32. Internal compute bf16 MFMA / fp32 accumulate.
// R5: attn rebalanced (64-row q-tiles, qt remap over b), XOR-swizzled LDS +
// global_load_lds width-16 staging (source-side swizzle keeps lane-linear dest).
// ws (44 MB): qb[B,H,S,HD] | kb[B,G,S,HD] | vb[B,G,S,HD] | vtb[B,G,HD,S] | ctx[B,S,H*HD] (bf16)

typedef __bf16 bf16_t;
using bf16x8 = __attribute__((ext_vector_type(8))) __bf16;
using f32x4  = __attribute__((ext_vector_type(4))) float;

#define LDSCP16(gp, lp)                                                       \
  __builtin_amdgcn_global_load_lds(                                           \
      (__attribute__((address_space(1))) void*)(gp),                          \
      (__attribute__((address_space(3))) void*)(lp), 16, 0, 0)

// ---------- shared 128x128-tile GEMM mainloop: C = A[M,K] * B[N,K]^T ----------
// LDS rows padded to 72 elements (144 B): b128 frag reads land 2-way (free).
// Explicit staging: global vector load (+cvt if fp32) -> ds_write_b128.
template <bool A_F32, bool B_F32>
__device__ __forceinline__ void gemm_tile(const void* __restrict__ AP,
                                          const void* __restrict__ BP, int K,
                                          int m0, int n0, bf16_t* As, bf16_t* Bs,
                                          f32x4 acc[4][4]) {
  const int tid = threadIdx.x;
  const int lane = tid & 63, w = tid >> 6;
  const int quad = lane >> 4, l16 = lane & 15;
  const int wm = (w >> 1) * 64, wn = (w & 1) * 64;
  const int nkt = K >> 6;
  for (int kt = 0; kt < nkt; ++kt) {
#pragma unroll
    for (int i = 0; i < 4; ++i) {
      int s = i * 256 + tid;
      int row = s >> 3, ch = s & 7;
      bf16x8 av, bv;
      if (A_F32) {
        const float* g = (const float*)AP + (size_t)(m0 + row) * K + kt * 64 + ch * 8;
        f32x4 u0 = *(const f32x4*)g;
        f32x4 u1 = *(const f32x4*)(g + 4);
        av[0] = (bf16_t)u0[0]; av[1] = (bf16_t)u0[1]; av[2] = (bf16_t)u0[2]; av[3] = (bf16_t)u0[3];
        av[4] = (bf16_t)u1[0]; av[5] = (bf16_t)u1[1]; av[6] = (bf16_t)u1[2]; av[7] = (bf16_t)u1[3];
      } else {
        av = *(const bf16x8*)((const bf16_t*)AP + (size_t)(m0 + row) * K + kt * 64 + ch * 8);
      }
      if (B_F32) {
        const float* g = (const float*)BP + (size_t)(n0 + row) * K + kt * 64 + ch * 8;
        f32x4 u0 = *(const f32x4*)g;
        f32x4 u1 = *(const f32x4*)(g + 4);
        bv[0] = (bf16_t)u0[0]; bv[1] = (bf16_t)u0[1]; bv[2] = (bf16_t)u0[2]; bv[3] = (bf16_t)u0[3];
        bv[4] = (bf16_t)u1[0]; bv[5] = (bf16_t)u1[1]; bv[6] = (bf16_t)u1[2]; bv[7] = (bf16_t)u1[3];
      } else {
        bv = *(const bf16x8*)((const bf16_t*)BP + (size_t)(n0 + row) * K + kt * 64 + ch * 8);
      }
      *(bf16x8*)(As + row * 72 + ch * 8) = av;
      *(bf16x8*)(Bs + row * 72 + ch * 8) = bv;
    }
    __syncthreads();
#pragma unroll
    for (int kk = 0; kk < 2; ++kk) {
      bf16x8 af[4], bfv[4];
#pragma unroll
      for (int i = 0; i < 4; ++i) {
        af[i]  = *(const bf16x8*)(As + (wm + i * 16 + l16) * 72 + kk * 32 + quad * 8);
        bfv[i] = *(const bf16x8*)(Bs + (wn + i * 16 + l16) * 72 + kk * 32 + quad * 8);
      }
#pragma unroll
      for (int im = 0; im < 4; ++im)
#pragma unroll
        for (int in_ = 0; in_ < 4; ++in_)
          acc[im][in_] = __builtin_amdgcn_mfma_f32_16x16x32_bf16(
              af[im], bfv[in_], acc[im][in_], 0, 0, 0);
    }
    __syncthreads();
  }
}

// ---------- fused QKV projection; writes head-major [B,Hn,S,HD] bf16 ----------
__global__ __launch_bounds__(256) void qkv_gemm(
    const float* __restrict__ x, const float* __restrict__ Wq,
    const float* __restrict__ Wk, const float* __restrict__ Wv,
    bf16_t* __restrict__ qo, bf16_t* __restrict__ ko, bf16_t* __restrict__ vo) {
  __shared__ __align__(16) bf16_t As[128 * 72];
  __shared__ __align__(16) bf16_t Bs[128 * 72];
  const int n0g = blockIdx.x * 128;  // 0..3071 over [q|k|v]
  const int m0 = blockIdx.y * 128;
  const float* B;
  bf16_t* O;
  int Hn, n0;
  if (n0g < 2048)      { B = Wq; O = qo; Hn = 16; n0 = n0g; }
  else if (n0g < 2560) { B = Wk; O = ko; Hn = 4;  n0 = n0g - 2048; }
  else                 { B = Wv; O = vo; Hn = 4;  n0 = n0g - 2560; }
  f32x4 acc[4][4] = {};
  gemm_tile<true, true>(x, B, 2048, m0, n0, As, Bs, acc);
  const int lane = threadIdx.x & 63, w = threadIdx.x >> 6;
  const int quad = lane >> 4, l16 = lane & 15;
  const int wm = (w >> 1) * 64, wn = (w & 1) * 64;
#pragma unroll
  for (int im = 0; im < 4; ++im)
#pragma unroll
    for (int in_ = 0; in_ < 4; ++in_)
#pragma unroll
      for (int r = 0; r < 4; ++r) {
        int gr = m0 + wm + im * 16 + quad * 4 + r;   // row = b*S+s
        int gc = n0 + wn + in_ * 16 + l16;           // col = h*HD+d
        int bb = gr >> 11, ss = gr & 2047, hh = gc >> 7, dd = gc & 127;
        O[(((size_t)bb * Hn + hh) * 2048 + ss) * 128 + dd] = (bf16_t)acc[im][in_][r];
      }
}

// ---------- output projection: out[B*S,2048] = ctx(bf16) * Wo(fp32)^T, fp32 out
__global__ __launch_bounds__(256) void out_gemm(const bf16_t* __restrict__ ctx,
                                                const float* __restrict__ Wo,
                                                float* __restrict__ out) {
  __shared__ __align__(16) bf16_t As[128 * 72];
  __shared__ __align__(16) bf16_t Bs[128 * 72];
  const int n0 = blockIdx.x * 128, m0 = blockIdx.y * 128;
  f32x4 acc[4][4] = {};
  gemm_tile<false, true>(ctx, Wo, 2048, m0, n0, As, Bs, acc);
  const int lane = threadIdx.x & 63, w = threadIdx.x >> 6;
  const int quad = lane >> 4, l16 = lane & 15;
  const int wm = (w >> 1) * 64, wn = (w & 1) * 64;
#pragma unroll
  for (int im = 0; im < 4; ++im)
#pragma unroll
    for (int in_ = 0; in_ < 4; ++in_)
#pragma unroll
      for (int r = 0; r < 4; ++r) {
        int gr = m0 + wm + im * 16 + quad * 4 + r;
        int gc = n0 + wn + in_ * 16 + l16;
        out[(size_t)gr * 2048 + gc] = acc[im][in_][r];
      }
}

// ---------- RMSNorm + RoPE (in place on bf16 scratch), one wave per row ------
__global__ __launch_bounds__(256) void rmsnorm_rope(bf16_t* __restrict__ x,
    const float* __restrict__ wgt, const float* __restrict__ cs,
    const float* __restrict__ sn, float outscale) {
  const int row = blockIdx.x * 4 + (threadIdx.x >> 6);
  const int lane = threadIdx.x & 63;
  const int pos = row & 2047;  // S=2048
  bf16_t* p = x + (size_t)row * 128;
  float v1 = (float)p[lane];
  float v2 = (float)p[lane + 64];
  float ss = v1 * v1 + v2 * v2;
#pragma unroll
  for (int m = 32; m; m >>= 1) ss += __shfl_xor(ss, m);
  float rr = rsqrtf(ss * (1.0f / 128.0f) + 1e-6f);
  float n1 = v1 * rr * wgt[lane];
  float n2 = v2 * rr * wgt[lane + 64];
  float c1 = cs[pos * 128 + lane],      s1 = sn[pos * 128 + lane];
  float c2 = cs[pos * 128 + lane + 64], s2 = sn[pos * 128 + lane + 64];
  p[lane]      = (bf16_t)((n1 * c1 - n2 * s1) * outscale);
  p[lane + 64] = (bf16_t)((n2 * c2 + n1 * s2) * outscale);
}

// ---------- V transpose: [BG,S,HD] -> [BG,HD,S] so PV B-frags are k-contig ---
__global__ __launch_bounds__(256) void vtrans(const bf16_t* __restrict__ v,
                                              bf16_t* __restrict__ vt) {
  __shared__ bf16_t t[64][72];
  const int bg = blockIdx.z, t0 = blockIdx.x * 64, d0 = blockIdx.y * 64;
  const int tid = threadIdx.x;
  const int r = tid >> 3, c = (tid & 7) * 8;
  const bf16_t* src = v + ((size_t)bg * 2048 + t0) * 128 + d0;
#pragma unroll
  for (int it = 0; it < 2; ++it) {
    uint4 val = *(const uint4*)(src + (size_t)(r + it * 32) * 128 + c);
    *(uint4*)&t[r + it * 32][c] = val;
  }
  __syncthreads();
#pragma unroll
  for (int it = 0; it < 2; ++it) {
    int d = r + it * 32;
    bf16_t tmp[8];
#pragma unroll
    for (int j = 0; j < 8; ++j) tmp[j] = t[c + j][d];
    *(uint4*)(vt + ((size_t)bg * 128 + d0 + d) * 2048 + t0 + c) = *(uint4*)tmp;
  }
}

// ---------- flash attention: 64 q-rows/block, K-tile=128, online softmax ----
// grid (32,16,2); qt remapped over b so co-resident blocks have complementary
// causal work. K/V staged via global_load_lds w16 with SOURCE-side XOR chunk
// swizzle (LDS dest stays lane-linear); frag reads use slot = chunk^(row&15)
// -> 2-way (free). P (64x128) overlays Klds with the same swizzle.
__global__ __launch_bounds__(256) void attn_kernel(const bf16_t* __restrict__ q,
    const bf16_t* __restrict__ k, const bf16_t* __restrict__ vt,
    bf16_t* __restrict__ ctx) {
  __shared__ __align__(16) bf16_t Klds[128 * 128];
  __shared__ __align__(16) bf16_t Vlds[128 * 128];
  char* KB = (char*)Klds;
  char* VB = (char*)Vlds;
  const int qi = blockIdx.x, h = blockIdx.y, b = blockIdx.z;
  const int qt = b ? 31 - qi : qi;  // 64-row q-tile index, balance remap
  const int g = h >> 2;             // GS = 4
  const int tid = threadIdx.x, w = tid >> 6, lane = tid & 63;
  const int quad = lane >> 4, l16 = lane & 15;
  const bf16_t* qp = q + (((size_t)b * 16 + h) * 2048 + (size_t)qt * 64) * 128;
  const bf16_t* kp = k + ((size_t)b * 4 + g) * 2048 * 128;
  const bf16_t* vtp = vt + ((size_t)b * 4 + g) * 128 * 2048;

  // Q A-fragments straight from global (k-contiguous 16B per lane); 16 rows/wave
  bf16x8 qf[4];
#pragma unroll
  for (int kk = 0; kk < 4; ++kk)
    qf[kk] = *(const bf16x8*)(qp + (size_t)(w * 16 + l16) * 128 + kk * 32 + quad * 8);

  f32x4 oacc[8] = {};
  float mrun[4], lrun[4];
#pragma unroll
  for (int r = 0; r < 4; ++r) { mrun[r] = -1e30f; lrun[r] = 0.f; }

  const int nkt = (qt >> 1) + 1;
  for (int kt = 0; kt < nkt; ++kt) {
    const bf16_t* ksrc = kp + (size_t)kt * 128 * 128;
    const bf16_t* vsrc = vtp + kt * 128;
#pragma unroll
    for (int i = 0; i < 8; ++i) {
      int s = i * 256 + tid;             // 16B chunk index, 0..2047
      int row = s >> 4, ch = s & 15;
      int sc = ch ^ (row & 15);          // source-side swizzle
      LDSCP16(ksrc + (size_t)row * 128 + sc * 8, Klds + s * 8);
      LDSCP16(vsrc + (size_t)row * 2048 + sc * 8, Vlds + s * 8);
    }
    __syncthreads();

    // S = Q * K^T  (16 q-rows per wave)
    f32x4 sacc[8] = {};
#pragma unroll
    for (int kk = 0; kk < 4; ++kk)
#pragma unroll
      for (int nt = 0; nt < 8; ++nt) {
        int trow = nt * 16 + l16;        // trow&15 == l16
        bf16x8 kf = *(const bf16x8*)(KB + trow * 256 + (((kk * 4 + quad) ^ l16) << 4));
        sacc[nt] = __builtin_amdgcn_mfma_f32_16x16x32_bf16(qf[kk], kf, sacc[nt], 0, 0, 0);
      }

    if (kt == nkt - 1) {  // tile containing the diagonal: mask kcol > qrow
      int qrow = qt * 64 + w * 16 + quad * 4;
#pragma unroll
      for (int nt = 0; nt < 8; ++nt) {
        int kcol = kt * 128 + nt * 16 + l16;
#pragma unroll
        for (int r = 0; r < 4; ++r)
          if (kcol > qrow + r) sacc[nt][r] = -1e30f;
      }
    }

    // online softmax: a C-tile row lives in the 16 lanes sharing `quad`
#pragma unroll
    for (int r = 0; r < 4; ++r) {
      float tm = sacc[0][r];
#pragma unroll
      for (int nt = 1; nt < 8; ++nt) tm = fmaxf(tm, sacc[nt][r]);
      tm = fmaxf(tm, __shfl_xor(tm, 1));
      tm = fmaxf(tm, __shfl_xor(tm, 2));
      tm = fmaxf(tm, __shfl_xor(tm, 4));
      tm = fmaxf(tm, __shfl_xor(tm, 8));
      float mn = fmaxf(mrun[r], tm);
      float al = exp2f((mrun[r] - mn) * 1.44269504f);
      mrun[r] = mn;
      float rs = 0.f;
#pragma unroll
      for (int nt = 0; nt < 8; ++nt) {
        float pv = exp2f((sacc[nt][r] - mn) * 1.44269504f);
        sacc[nt][r] = pv;
        rs += pv;
      }
      rs += __shfl_xor(rs, 1);
      rs += __shfl_xor(rs, 2);
      rs += __shfl_xor(rs, 4);
      rs += __shfl_xor(rs, 8);
      lrun[r] = lrun[r] * al + rs;
#pragma unroll
      for (int nd = 0; nd < 8; ++nd) oacc[nd][r] *= al;
    }

    __syncthreads();  // all waves done reading K before P overlays it

    // write P (C-layout scatter) into Klds rows 0..63, chunk-swizzled
#pragma unroll
    for (int nt = 0; nt < 8; ++nt) {
      int c = nt * 2 + (l16 >> 3);
#pragma unroll
      for (int r = 0; r < 4; ++r) {
        int prow = w * 16 + quad * 4 + r;   // prow&15 == quad*4+r
        *(bf16_t*)(KB + prow * 256 + ((c ^ (prow & 15)) << 4) + ((l16 & 7) << 1)) =
            (bf16_t)sacc[nt][r];
      }
    }
    __syncthreads();

    // O += P * V   (A = P from LDS, B = V^T tile, k-contiguous)
#pragma unroll
    for (int kkp = 0; kkp < 4; ++kkp) {
      int prow = w * 16 + l16;              // prow&15 == l16
      bf16x8 pf = *(const bf16x8*)(KB + prow * 256 + (((kkp * 4 + quad) ^ l16) << 4));
#pragma unroll
      for (int nd = 0; nd < 8; ++nd) {
        int d = nd * 16 + l16;              // d&15 == l16
        bf16x8 vf = *(const bf16x8*)(VB + d * 256 + (((kkp * 4 + quad) ^ l16) << 4));
        oacc[nd] = __builtin_amdgcn_mfma_f32_16x16x32_bf16(pf, vf, oacc[nd], 0, 0, 0);
      }
    }
    __syncthreads();  // all reads done before next staging overwrites tiles
  }

  // epilogue: ctx[b][pos][h][d] = O / l
#pragma unroll
  for (int r = 0; r < 4; ++r) {
    float inv = 1.f / lrun[r];
    int pos = qt * 64 + w * 16 + quad * 4 + r;
    size_t base = (((size_t)b * 2048 + pos) * 16 + h) * 128;
#pragma unroll
    for (int nd = 0; nd < 8; ++nd)
      ctx[base + nd * 16 + l16] = (bf16_t)(oacc[nd][r] * inv);
  }
}

extern "C" void kernel_launch(void* const* d_in, const int* in_sizes, int n_in,
                              void* d_out, int out_size, void* d_ws, size_t ws_size,
                              hipStream_t stream) {
  (void)in_sizes; (void)n_in; (void)out_size; (void)ws_size;
  const float* x    = (const float*)d_in[0];
  // d_in[1] = mask (causal, structural -> unused)
  const float* cosp = (const float*)d_in[2];
  const float* sinp = (const float*)d_in[3];
  const float* Wq   = (const float*)d_in[4];
  const float* Wk   = (const float*)d_in[5];
  const float* Wv   = (const float*)d_in[6];
  const float* Wo   = (const float*)d_in[7];
  const float* qnw  = (const float*)d_in[8];
  const float* knw  = (const float*)d_in[9];
  float* out = (float*)d_out;

  char* ws = (char*)d_ws;
  bf16_t* qb  = (bf16_t*)(ws);               // 16777216 B
  bf16_t* kb  = (bf16_t*)(ws + 16777216);    //  4194304 B
  bf16_t* vb  = (bf16_t*)(ws + 20971520);    //  4194304 B
  bf16_t* vtb = (bf16_t*)(ws + 25165824);    //  4194304 B
  bf16_t* ctx = (bf16_t*)(ws + 29360128);    // 16777216 B  (total 46137344 B)

  qkv_gemm<<<dim3(24, 32), 256, 0, stream>>>(x, Wq, Wk, Wv, qb, kb, vb);
  rmsnorm_rope<<<16384, 256, 0, stream>>>(qb, qnw, cosp, sinp, 0.08838834764831845f);
  rmsnorm_rope<<<4096, 256, 0, stream>>>(kb, knw, cosp, sinp, 1.0f);
  vtrans<<<dim3(32, 2, 8), 256, 0, stream>>>(vb, vtb);
  attn_kernel<<<dim3(32, 16, 2), 256, 0, stream>>>(qb, kb, vtb, ctx);
  out_gemm<<<dim3(16, 32), 256, 0, stream>>>(ctx, Wo, out);
}

// Round 6
// 490.487 us; speedup vs baseline: 1.4754x; 1.1799x over previous
//
#include <hip/hip_runtime.h>
#include <hip/hip_bf16.h>

// GroupedQueryAttention: B=2,S=2048,D=2048,H=16,G=4,HD=128, causal, rmsnorm+rope.
// Inputs fp32; OUTPUT fp32. Internal compute bf16 MFMA / fp32 accumulate.
// R6: attn rewritten as barrier-light flash: direct-global K/V fragment reads
// (wave-partitioned by kcol / d, no staging redundancy), fixed-base softmax
// (log2e*HD^-0.5 folded into q scale -> no running max / rescale / shuffles),
// ping-pong LDS P (one barrier/iter), 4 blocks/CU.
// ws (44 MB): qb[B,H,S,HD] | kb[B,G,S,HD] | vb[B,G,S,HD] | vtb[B,G,HD,S] | ctx[B,S,H*HD] (bf16)

typedef __bf16 bf16_t;
using bf16x8 = __attribute__((ext_vector_type(8))) __bf16;
using f32x4  = __attribute__((ext_vector_type(4))) float;

// ---------- shared 128x128-tile GEMM mainloop: C = A[M,K] * B[N,K]^T ----------
// LDS rows padded to 72 elements (144 B): b128 frag reads land 2-way (free).
template <bool A_F32, bool B_F32>
__device__ __forceinline__ void gemm_tile(const void* __restrict__ AP,
                                          const void* __restrict__ BP, int K,
                                          int m0, int n0, bf16_t* As, bf16_t* Bs,
                                          f32x4 acc[4][4]) {
  const int tid = threadIdx.x;
  const int lane = tid & 63, w = tid >> 6;
  const int quad = lane >> 4, l16 = lane & 15;
  const int wm = (w >> 1) * 64, wn = (w & 1) * 64;
  const int nkt = K >> 6;
  for (int kt = 0; kt < nkt; ++kt) {
#pragma unroll
    for (int i = 0; i < 4; ++i) {
      int s = i * 256 + tid;
      int row = s >> 3, ch = s & 7;
      bf16x8 av, bv;
      if (A_F32) {
        const float* g = (const float*)AP + (size_t)(m0 + row) * K + kt * 64 + ch * 8;
        f32x4 u0 = *(const f32x4*)g;
        f32x4 u1 = *(const f32x4*)(g + 4);
        av[0] = (bf16_t)u0[0]; av[1] = (bf16_t)u0[1]; av[2] = (bf16_t)u0[2]; av[3] = (bf16_t)u0[3];
        av[4] = (bf16_t)u1[0]; av[5] = (bf16_t)u1[1]; av[6] = (bf16_t)u1[2]; av[7] = (bf16_t)u1[3];
      } else {
        av = *(const bf16x8*)((const bf16_t*)AP + (size_t)(m0 + row) * K + kt * 64 + ch * 8);
      }
      if (B_F32) {
        const float* g = (const float*)BP + (size_t)(n0 + row) * K + kt * 64 + ch * 8;
        f32x4 u0 = *(const f32x4*)g;
        f32x4 u1 = *(const f32x4*)(g + 4);
        bv[0] = (bf16_t)u0[0]; bv[1] = (bf16_t)u0[1]; bv[2] = (bf16_t)u0[2]; bv[3] = (bf16_t)u0[3];
        bv[4] = (bf16_t)u1[0]; bv[5] = (bf16_t)u1[1]; bv[6] = (bf16_t)u1[2]; bv[7] = (bf16_t)u1[3];
      } else {
        bv = *(const bf16x8*)((const bf16_t*)BP + (size_t)(n0 + row) * K + kt * 64 + ch * 8);
      }
      *(bf16x8*)(As + row * 72 + ch * 8) = av;
      *(bf16x8*)(Bs + row * 72 + ch * 8) = bv;
    }
    __syncthreads();
#pragma unroll
    for (int kk = 0; kk < 2; ++kk) {
      bf16x8 af[4], bfv[4];
#pragma unroll
      for (int i = 0; i < 4; ++i) {
        af[i]  = *(const bf16x8*)(As + (wm + i * 16 + l16) * 72 + kk * 32 + quad * 8);
        bfv[i] = *(const bf16x8*)(Bs + (wn + i * 16 + l16) * 72 + kk * 32 + quad * 8);
      }
#pragma unroll
      for (int im = 0; im < 4; ++im)
#pragma unroll
        for (int in_ = 0; in_ < 4; ++in_)
          acc[im][in_] = __builtin_amdgcn_mfma_f32_16x16x32_bf16(
              af[im], bfv[in_], acc[im][in_], 0, 0, 0);
    }
    __syncthreads();
  }
}

// ---------- fused QKV projection; writes head-major [B,Hn,S,HD] bf16 ----------
__global__ __launch_bounds__(256) void qkv_gemm(
    const float* __restrict__ x, const float* __restrict__ Wq,
    const float* __restrict__ Wk, const float* __restrict__ Wv,
    bf16_t* __restrict__ qo, bf16_t* __restrict__ ko, bf16_t* __restrict__ vo) {
  __shared__ __align__(16) bf16_t As[128 * 72];
  __shared__ __align__(16) bf16_t Bs[128 * 72];
  const int n0g = blockIdx.x * 128;  // 0..3071 over [q|k|v]
  const int m0 = blockIdx.y * 128;
  const float* B;
  bf16_t* O;
  int Hn, n0;
  if (n0g < 2048)      { B = Wq; O = qo; Hn = 16; n0 = n0g; }
  else if (n0g < 2560) { B = Wk; O = ko; Hn = 4;  n0 = n0g - 2048; }
  else                 { B = Wv; O = vo; Hn = 4;  n0 = n0g - 2560; }
  f32x4 acc[4][4] = {};
  gemm_tile<true, true>(x, B, 2048, m0, n0, As, Bs, acc);
  const int lane = threadIdx.x & 63, w = threadIdx.x >> 6;
  const int quad = lane >> 4, l16 = lane & 15;
  const int wm = (w >> 1) * 64, wn = (w & 1) * 64;
#pragma unroll
  for (int im = 0; im < 4; ++im)
#pragma unroll
    for (int in_ = 0; in_ < 4; ++in_)
#pragma unroll
      for (int r = 0; r < 4; ++r) {
        int gr = m0 + wm + im * 16 + quad * 4 + r;   // row = b*S+s
        int gc = n0 + wn + in_ * 16 + l16;           // col = h*HD+d
        int bb = gr >> 11, ss = gr & 2047, hh = gc >> 7, dd = gc & 127;
        O[(((size_t)bb * Hn + hh) * 2048 + ss) * 128 + dd] = (bf16_t)acc[im][in_][r];
      }
}

// ---------- output projection: out[B*S,2048] = ctx(bf16) * Wo(fp32)^T, fp32 out
__global__ __launch_bounds__(256) void out_gemm(const bf16_t* __restrict__ ctx,
                                                const float* __restrict__ Wo,
                                                float* __restrict__ out) {
  __shared__ __align__(16) bf16_t As[128 * 72];
  __shared__ __align__(16) bf16_t Bs[128 * 72];
  const int n0 = blockIdx.x * 128, m0 = blockIdx.y * 128;
  f32x4 acc[4][4] = {};
  gemm_tile<false, true>(ctx, Wo, 2048, m0, n0, As, Bs, acc);
  const int lane = threadIdx.x & 63, w = threadIdx.x >> 6;
  const int quad = lane >> 4, l16 = lane & 15;
  const int wm = (w >> 1) * 64, wn = (w & 1) * 64;
#pragma unroll
  for (int im = 0; im < 4; ++im)
#pragma unroll
    for (int in_ = 0; in_ < 4; ++in_)
#pragma unroll
      for (int r = 0; r < 4; ++r) {
        int gr = m0 + wm + im * 16 + quad * 4 + r;
        int gc = n0 + wn + in_ * 16 + l16;
        out[(size_t)gr * 2048 + gc] = acc[im][in_][r];
      }
}

// ---------- RMSNorm + RoPE (in place on bf16 scratch), one wave per row ------
__global__ __launch_bounds__(256) void rmsnorm_rope(bf16_t* __restrict__ x,
    const float* __restrict__ wgt, const float* __restrict__ cs,
    const float* __restrict__ sn, float outscale) {
  const int row = blockIdx.x * 4 + (threadIdx.x >> 6);
  const int lane = threadIdx.x & 63;
  const int pos = row & 2047;  // S=2048
  bf16_t* p = x + (size_t)row * 128;
  float v1 = (float)p[lane];
  float v2 = (float)p[lane + 64];
  float ss = v1 * v1 + v2 * v2;
#pragma unroll
  for (int m = 32; m; m >>= 1) ss += __shfl_xor(ss, m);
  float rr = rsqrtf(ss * (1.0f / 128.0f) + 1e-6f);
  float n1 = v1 * rr * wgt[lane];
  float n2 = v2 * rr * wgt[lane + 64];
  float c1 = cs[pos * 128 + lane],      s1 = sn[pos * 128 + lane];
  float c2 = cs[pos * 128 + lane + 64], s2 = sn[pos * 128 + lane + 64];
  p[lane]      = (bf16_t)((n1 * c1 - n2 * s1) * outscale);
  p[lane + 64] = (bf16_t)((n2 * c2 + n1 * s2) * outscale);
}

// ---------- V transpose: [BG,S,HD] -> [BG,HD,S] so PV B-frags are k-contig ---
__global__ __launch_bounds__(256) void vtrans(const bf16_t* __restrict__ v,
                                              bf16_t* __restrict__ vt) {
  __shared__ bf16_t t[64][72];
  const int bg = blockIdx.z, t0 = blockIdx.x * 64, d0 = blockIdx.y * 64;
  const int tid = threadIdx.x;
  const int r = tid >> 3, c = (tid & 7) * 8;
  const bf16_t* src = v + ((size_t)bg * 2048 + t0) * 128 + d0;
#pragma unroll
  for (int it = 0; it < 2; ++it) {
    uint4 val = *(const uint4*)(src + (size_t)(r + it * 32) * 128 + c);
    *(uint4*)&t[r + it * 32][c] = val;
  }
  __syncthreads();
#pragma unroll
  for (int it = 0; it < 2; ++it) {
    int d = r + it * 32;
    bf16_t tmp[8];
#pragma unroll
    for (int j = 0; j < 8; ++j) tmp[j] = t[c + j][d];
    *(uint4*)(vt + ((size_t)bg * 128 + d0 + d) * 2048 + t0 + c) = *(uint4*)tmp;
  }
}

// ---------- flash attention, barrier-light ----------
// Block = (qi, h, b): 32 q-rows; K-loop in 64-col tiles.
// QK: wave w owns kcols [16w,16w+16)  -> kf loaded once per block (no redundancy).
// PV: wave w owns d-slice [32w,32w+32) -> vf loaded once per block.
// P (32x64) round-trips through ping-pong LDS; ONE __syncthreads per iteration.
// Fixed-base softmax: q pre-scaled by HD^-0.5*log2e, pv = exp2(s); per-lane
// partial row sums, reduced once in the epilogue.
__global__ __launch_bounds__(256, 4) void attn_kernel(const bf16_t* __restrict__ q,
    const bf16_t* __restrict__ k, const bf16_t* __restrict__ vt,
    bf16_t* __restrict__ ctx) {
  __shared__ __align__(16) bf16_t Plds[2][32][72];  // 9216 B, ping-pong
  __shared__ __align__(16) float lred[32][4];       //  512 B
  const int qi = blockIdx.x, h = blockIdx.y, b = blockIdx.z;
  const int qt = ((b ^ (h >> 3)) & 1) ? 63 - qi : qi;  // balance remap
  const int g = h >> 2;  // GS = 4
  const int tid = threadIdx.x, w = tid >> 6, lane = tid & 63;
  const int quad = lane >> 4, l16 = lane & 15;
  const bf16_t* qp = q + (((size_t)b * 16 + h) * 2048 + (size_t)qt * 32) * 128;
  const bf16_t* kp = k + ((size_t)b * 4 + g) * 2048 * 128 +
                     (size_t)(w * 16 + l16) * 128 + quad * 8;
  const bf16_t* vp = vt + ((size_t)b * 4 + g) * 128 * 2048 +
                     (size_t)(w * 32 + l16) * 2048 + quad * 8;

  // Q A-fragments (q-rows mt*16+l16), loop-invariant (32 VGPR)
  bf16x8 qf[2][4];
#pragma unroll
  for (int mt = 0; mt < 2; ++mt)
#pragma unroll
    for (int kk = 0; kk < 4; ++kk)
      qf[mt][kk] = *(const bf16x8*)(qp + (size_t)(mt * 16 + l16) * 128 +
                                    kk * 32 + quad * 8);

  f32x4 oacc[2][2] = {};
  float lsum[2][4] = {};
  const int nkt = (qt >> 1) + 1;
  for (int kt = 0; kt < nkt; ++kt) {
    // K fragments: rows kt*64 + w*16 + l16 (wave-owned 16 kcols)
    const bf16_t* kro = kp + (size_t)kt * 64 * 128;
    bf16x8 kf[4];
#pragma unroll
    for (int kk = 0; kk < 4; ++kk) kf[kk] = *(const bf16x8*)(kro + kk * 32);
    // V fragments: d = w*32 + nd*16 + l16, k-cols kt*64.. (wave-owned d-slice)
    const bf16_t* vro = vp + (size_t)kt * 64;
    bf16x8 vf[2][2];
#pragma unroll
    for (int nd = 0; nd < 2; ++nd)
#pragma unroll
      for (int kkp = 0; kkp < 2; ++kkp)
        vf[nd][kkp] = *(const bf16x8*)(vro + (size_t)nd * 16 * 2048 + kkp * 32);

    // S = Q K^T for this wave's 16 kcols
    f32x4 sacc[2] = {};
#pragma unroll
    for (int kk = 0; kk < 4; ++kk)
#pragma unroll
      for (int mt = 0; mt < 2; ++mt)
        sacc[mt] = __builtin_amdgcn_mfma_f32_16x16x32_bf16(qf[mt][kk], kf[kk],
                                                           sacc[mt], 0, 0, 0);
    if (kt == nkt - 1) {  // diagonal tile: mask kcol > qrow
      int kcol = kt * 64 + w * 16 + l16;
#pragma unroll
      for (int mt = 0; mt < 2; ++mt) {
        int qrow = qt * 32 + mt * 16 + quad * 4;
#pragma unroll
        for (int r = 0; r < 4; ++r)
          if (kcol > qrow + r) sacc[mt][r] = -1e30f;
      }
    }

    // fixed-base softmax numerator + P write (C-layout scatter, 8 b16 stores)
    const int pb = kt & 1;
#pragma unroll
    for (int mt = 0; mt < 2; ++mt)
#pragma unroll
      for (int r = 0; r < 4; ++r) {
        float pv = exp2f(sacc[mt][r]);
        lsum[mt][r] += pv;
        Plds[pb][mt * 16 + quad * 4 + r][w * 16 + l16] = (bf16_t)pv;
      }
    __syncthreads();  // the only barrier in the loop

    // O += P * V for this wave's 32-wide d-slice
#pragma unroll
    for (int kkp = 0; kkp < 2; ++kkp) {
      bf16x8 pf[2];
#pragma unroll
      for (int mt = 0; mt < 2; ++mt)
        pf[mt] = *(const bf16x8*)&Plds[pb][mt * 16 + l16][kkp * 32 + quad * 8];
#pragma unroll
      for (int nd = 0; nd < 2; ++nd)
#pragma unroll
        for (int mt = 0; mt < 2; ++mt)
          oacc[mt][nd] = __builtin_amdgcn_mfma_f32_16x16x32_bf16(
              pf[mt], vf[nd][kkp], oacc[mt][nd], 0, 0, 0);
    }
  }

  // row-sum: reduce per-lane partials over the 16-lane group, then over waves
#pragma unroll
  for (int mt = 0; mt < 2; ++mt)
#pragma unroll
    for (int r = 0; r < 4; ++r) {
      float v = lsum[mt][r];
      v += __shfl_xor(v, 1);
      v += __shfl_xor(v, 2);
      v += __shfl_xor(v, 4);
      v += __shfl_xor(v, 8);
      if (l16 == 0) lred[mt * 16 + quad * 4 + r][w] = v;
    }
  __syncthreads();
#pragma unroll
  for (int mt = 0; mt < 2; ++mt)
#pragma unroll
    for (int r = 0; r < 4; ++r) {
      int row = mt * 16 + quad * 4 + r;
      f32x4 t = *(const f32x4*)lred[row];
      float inv = 1.f / (t[0] + t[1] + t[2] + t[3]);
      int pos = qt * 32 + row;
      size_t base = (((size_t)b * 2048 + pos) * 16 + h) * 128;
#pragma unroll
      for (int nd = 0; nd < 2; ++nd)
        ctx[base + w * 32 + nd * 16 + l16] = (bf16_t)(oacc[mt][nd][r] * inv);
    }
}

extern "C" void kernel_launch(void* const* d_in, const int* in_sizes, int n_in,
                              void* d_out, int out_size, void* d_ws, size_t ws_size,
                              hipStream_t stream) {
  (void)in_sizes; (void)n_in; (void)out_size; (void)ws_size;
  const float* x    = (const float*)d_in[0];
  // d_in[1] = mask (causal, structural -> unused)
  const float* cosp = (const float*)d_in[2];
  const float* sinp = (const float*)d_in[3];
  const float* Wq   = (const float*)d_in[4];
  const float* Wk   = (const float*)d_in[5];
  const float* Wv   = (const float*)d_in[6];
  const float* Wo   = (const float*)d_in[7];
  const float* qnw  = (const float*)d_in[8];
  const float* knw  = (const float*)d_in[9];
  float* out = (float*)d_out;

  char* ws = (char*)d_ws;
  bf16_t* qb  = (bf16_t*)(ws);               // 16777216 B
  bf16_t* kb  = (bf16_t*)(ws + 16777216);    //  4194304 B
  bf16_t* vb  = (bf16_t*)(ws + 20971520);    //  4194304 B
  bf16_t* vtb = (bf16_t*)(ws + 25165824);    //  4194304 B
  bf16_t* ctx = (bf16_t*)(ws + 29360128);    // 16777216 B  (total 46137344 B)

  qkv_gemm<<<dim3(24, 32), 256, 0, stream>>>(x, Wq, Wk, Wv, qb, kb, vb);
  // q scale = HD^-0.5 * log2(e) folded for fixed-base exp2 softmax
  rmsnorm_rope<<<16384, 256, 0, stream>>>(qb, qnw, cosp, sinp, 0.12751742902f);
  rmsnorm_rope<<<4096, 256, 0, stream>>>(kb, knw, cosp, sinp, 1.0f);
  vtrans<<<dim3(32, 2, 8), 256, 0, stream>>>(vb, vtb);
  attn_kernel<<<dim3(64, 16, 2), 256, 0, stream>>>(qb, kb, vtb, ctx);
  out_gemm<<<dim3(16, 32), 256, 0, stream>>>(ctx, Wo, out);
}

// Round 7
// 441.493 us; speedup vs baseline: 1.6392x; 1.1110x over previous
//
#include <hip/hip_runtime.h>
#include <hip/hip_bf16.h>

// GroupedQueryAttention: B=2,S=2048,D=2048,H=16,G=4,HD=128, causal, rmsnorm+rope.
// Inputs fp32; OUTPUT fp32. Internal compute bf16 MFMA / fp32 accumulate.
// R7: (1) pre-cast x/W* to bf16 once; GEMMs use global_load_lds w16 + XOR swizzle
// (R5-proven zero-conflict staging, no in-loop cvt). (2) attn: kf register
// double-buffer prefetch -> global latency off the critical path.
// ws (58.7 MB):
//   qb  [B,H,S,HD]  @ 0         (16.78 MB)
//   kb  [B,G,S,HD]  @ 16777216  ( 4.19 MB)
//   vb  [B,G,S,HD]  @ 20971520  ( 4.19 MB)
//   vtb [B,G,HD,S]  @ 25165824  ( 4.19 MB)
//   ctx [B,S,H*HD]  @ 29360128  (16.78 MB)  -- xb (bf16 x) aliases this region
//   wqb/wob         @ 46137344  ( 8.39 MB)  -- wob cast after qkv consumed wqb
//   wkb             @ 54525952  ( 2.10 MB)
//   wvb             @ 56623104  ( 2.10 MB)

typedef __bf16 bf16_t;
using bf16x8 = __attribute__((ext_vector_type(8))) __bf16;
using f32x4  = __attribute__((ext_vector_type(4))) float;

#define LDSCP16(gp, lp)                                                       \
  __builtin_amdgcn_global_load_lds(                                           \
      (__attribute__((address_space(1))) void*)(gp),                          \
      (__attribute__((address_space(3))) void*)(lp), 16, 0, 0)

// ---------- fp32 -> bf16 bulk cast (memory-bound) ----------
__global__ __launch_bounds__(256) void cast_f32_bf16(const float* __restrict__ src,
                                                     bf16_t* __restrict__ dst) {
  size_t i = (size_t)blockIdx.x * 256 + threadIdx.x;
  const float* g = src + i * 8;
  f32x4 u0 = *(const f32x4*)g;
  f32x4 u1 = *(const f32x4*)(g + 4);
  bf16x8 v;
  v[0] = (bf16_t)u0[0]; v[1] = (bf16_t)u0[1]; v[2] = (bf16_t)u0[2]; v[3] = (bf16_t)u0[3];
  v[4] = (bf16_t)u1[0]; v[5] = (bf16_t)u1[1]; v[6] = (bf16_t)u1[2]; v[7] = (bf16_t)u1[3];
  *(bf16x8*)(dst + i * 8) = v;
}

// ---------- 128x128-tile GEMM mainloop: C = A[M,K] * B[N,K]^T (both bf16) ----
// Staging: global_load_lds width 16, source-side XOR chunk swizzle (8 chunks/row,
// slot = chunk ^ (row&7)); LDS dest lane-linear (wave-uniform + lane*16) per
// the m104/m108 constraint. Frag reads deswizzle -> 2-way conflicts (free).
__device__ __forceinline__ void gemm_tile(const bf16_t* __restrict__ A,
                                          const bf16_t* __restrict__ B, int K,
                                          int m0, int n0, bf16_t* As, bf16_t* Bs,
                                          f32x4 acc[4][4]) {
  const int tid = threadIdx.x;
  const int lane = tid & 63, w = tid >> 6;
  const int quad = lane >> 4, l16 = lane & 15;
  const int wm = (w >> 1) * 64, wn = (w & 1) * 64;
  char* AsB = (char*)As;
  char* BsB = (char*)Bs;
  const int nkt = K >> 6;
  for (int kt = 0; kt < nkt; ++kt) {
#pragma unroll
    for (int i = 0; i < 4; ++i) {
      int s = i * 256 + tid;          // 16B chunk id, 0..1023 (128 rows x 8)
      int row = s >> 3, ch = s & 7;
      int sc = ch ^ (row & 7);        // source-side swizzle
      LDSCP16(A + (size_t)(m0 + row) * K + kt * 64 + sc * 8, As + s * 8);
      LDSCP16(B + (size_t)(n0 + row) * K + kt * 64 + sc * 8, Bs + s * 8);
    }
    __syncthreads();
#pragma unroll
    for (int kk = 0; kk < 2; ++kk) {
      bf16x8 af[4], bfv[4];
#pragma unroll
      for (int i = 0; i < 4; ++i) {
        int ra = wm + i * 16 + l16;
        af[i] = *(const bf16x8*)(AsB + ra * 128 + (((kk * 4 + quad) ^ (ra & 7)) << 4));
        int rb = wn + i * 16 + l16;
        bfv[i] = *(const bf16x8*)(BsB + rb * 128 + (((kk * 4 + quad) ^ (rb & 7)) << 4));
      }
#pragma unroll
      for (int im = 0; im < 4; ++im)
#pragma unroll
        for (int in_ = 0; in_ < 4; ++in_)
          acc[im][in_] = __builtin_amdgcn_mfma_f32_16x16x32_bf16(
              af[im], bfv[in_], acc[im][in_], 0, 0, 0);
    }
    __syncthreads();
  }
}

// ---------- fused QKV projection; writes head-major [B,Hn,S,HD] bf16 ----------
__global__ __launch_bounds__(256) void qkv_gemm(
    const bf16_t* __restrict__ x, const bf16_t* __restrict__ Wq,
    const bf16_t* __restrict__ Wk, const bf16_t* __restrict__ Wv,
    bf16_t* __restrict__ qo, bf16_t* __restrict__ ko, bf16_t* __restrict__ vo) {
  __shared__ __align__(16) bf16_t As[128 * 64];
  __shared__ __align__(16) bf16_t Bs[128 * 64];
  const int n0g = blockIdx.x * 128;  // 0..3071 over [q|k|v]
  const int m0 = blockIdx.y * 128;
  const bf16_t* B;
  bf16_t* O;
  int Hn, n0;
  if (n0g < 2048)      { B = Wq; O = qo; Hn = 16; n0 = n0g; }
  else if (n0g < 2560) { B = Wk; O = ko; Hn = 4;  n0 = n0g - 2048; }
  else                 { B = Wv; O = vo; Hn = 4;  n0 = n0g - 2560; }
  f32x4 acc[4][4] = {};
  gemm_tile(x, B, 2048, m0, n0, As, Bs, acc);
  const int lane = threadIdx.x & 63, w = threadIdx.x >> 6;
  const int quad = lane >> 4, l16 = lane & 15;
  const int wm = (w >> 1) * 64, wn = (w & 1) * 64;
#pragma unroll
  for (int im = 0; im < 4; ++im)
#pragma unroll
    for (int in_ = 0; in_ < 4; ++in_)
#pragma unroll
      for (int r = 0; r < 4; ++r) {
        int gr = m0 + wm + im * 16 + quad * 4 + r;   // row = b*S+s
        int gc = n0 + wn + in_ * 16 + l16;           // col = h*HD+d
        int bb = gr >> 11, ss = gr & 2047, hh = gc >> 7, dd = gc & 127;
        O[(((size_t)bb * Hn + hh) * 2048 + ss) * 128 + dd] = (bf16_t)acc[im][in_][r];
      }
}

// ---------- output projection: out[B*S,2048] = ctx(bf16) * Wo(bf16)^T, fp32 out
__global__ __launch_bounds__(256) void out_gemm(const bf16_t* __restrict__ ctx,
                                                const bf16_t* __restrict__ Wo,
                                                float* __restrict__ out) {
  __shared__ __align__(16) bf16_t As[128 * 64];
  __shared__ __align__(16) bf16_t Bs[128 * 64];
  const int n0 = blockIdx.x * 128, m0 = blockIdx.y * 128;
  f32x4 acc[4][4] = {};
  gemm_tile(ctx, Wo, 2048, m0, n0, As, Bs, acc);
  const int lane = threadIdx.x & 63, w = threadIdx.x >> 6;
  const int quad = lane >> 4, l16 = lane & 15;
  const int wm = (w >> 1) * 64, wn = (w & 1) * 64;
#pragma unroll
  for (int im = 0; im < 4; ++im)
#pragma unroll
    for (int in_ = 0; in_ < 4; ++in_)
#pragma unroll
      for (int r = 0; r < 4; ++r) {
        int gr = m0 + wm + im * 16 + quad * 4 + r;
        int gc = n0 + wn + in_ * 16 + l16;
        out[(size_t)gr * 2048 + gc] = acc[im][in_][r];
      }
}

// ---------- RMSNorm + RoPE (in place on bf16 scratch), one wave per row ------
__global__ __launch_bounds__(256) void rmsnorm_rope(bf16_t* __restrict__ x,
    const float* __restrict__ wgt, const float* __restrict__ cs,
    const float* __restrict__ sn, float outscale) {
  const int row = blockIdx.x * 4 + (threadIdx.x >> 6);
  const int lane = threadIdx.x & 63;
  const int pos = row & 2047;  // S=2048
  bf16_t* p = x + (size_t)row * 128;
  float v1 = (float)p[lane];
  float v2 = (float)p[lane + 64];
  float ss = v1 * v1 + v2 * v2;
#pragma unroll
  for (int m = 32; m; m >>= 1) ss += __shfl_xor(ss, m);
  float rr = rsqrtf(ss * (1.0f / 128.0f) + 1e-6f);
  float n1 = v1 * rr * wgt[lane];
  float n2 = v2 * rr * wgt[lane + 64];
  float c1 = cs[pos * 128 + lane],      s1 = sn[pos * 128 + lane];
  float c2 = cs[pos * 128 + lane + 64], s2 = sn[pos * 128 + lane + 64];
  p[lane]      = (bf16_t)((n1 * c1 - n2 * s1) * outscale);
  p[lane + 64] = (bf16_t)((n2 * c2 + n1 * s2) * outscale);
}

// ---------- V transpose: [BG,S,HD] -> [BG,HD,S] so PV B-frags are k-contig ---
__global__ __launch_bounds__(256) void vtrans(const bf16_t* __restrict__ v,
                                              bf16_t* __restrict__ vt) {
  __shared__ bf16_t t[64][72];
  const int bg = blockIdx.z, t0 = blockIdx.x * 64, d0 = blockIdx.y * 64;
  const int tid = threadIdx.x;
  const int r = tid >> 3, c = (tid & 7) * 8;
  const bf16_t* src = v + ((size_t)bg * 2048 + t0) * 128 + d0;
#pragma unroll
  for (int it = 0; it < 2; ++it) {
    uint4 val = *(const uint4*)(src + (size_t)(r + it * 32) * 128 + c);
    *(uint4*)&t[r + it * 32][c] = val;
  }
  __syncthreads();
#pragma unroll
  for (int it = 0; it < 2; ++it) {
    int d = r + it * 32;
    bf16_t tmp[8];
#pragma unroll
    for (int j = 0; j < 8; ++j) tmp[j] = t[c + j][d];
    *(uint4*)(vt + ((size_t)bg * 128 + d0 + d) * 2048 + t0 + c) = *(uint4*)tmp;
  }
}

// ---------- flash attention, barrier-light + kf prefetch ----------
// Block = (qi, h, b): 32 q-rows; K-loop in 64-col tiles.
// QK: wave w owns kcols [16w,16w+16); kf double-buffered one tile ahead so
// global latency overlaps a full iteration. PV: wave w owns d-slice [32w,+32).
// P (32x64) ping-pong LDS; ONE __syncthreads per iteration. Fixed-base softmax
// (HD^-0.5*log2e folded into q scale): no running max / rescale / shuffles.
__global__ __launch_bounds__(256, 4) void attn_kernel(const bf16_t* __restrict__ q,
    const bf16_t* __restrict__ k, const bf16_t* __restrict__ vt,
    bf16_t* __restrict__ ctx) {
  __shared__ __align__(16) bf16_t Plds[2][32][72];  // 9216 B, ping-pong
  __shared__ __align__(16) float lred[32][4];       //  512 B
  const int qi = blockIdx.x, h = blockIdx.y, b = blockIdx.z;
  const int qt = ((b ^ (h >> 3)) & 1) ? 63 - qi : qi;  // balance remap
  const int g = h >> 2;  // GS = 4
  const int tid = threadIdx.x, w = tid >> 6, lane = tid & 63;
  const int quad = lane >> 4, l16 = lane & 15;
  const bf16_t* qp = q + (((size_t)b * 16 + h) * 2048 + (size_t)qt * 32) * 128;
  const bf16_t* kp = k + ((size_t)b * 4 + g) * 2048 * 128 +
                     (size_t)(w * 16 + l16) * 128 + quad * 8;
  const bf16_t* vp = vt + ((size_t)b * 4 + g) * 128 * 2048 +
                     (size_t)(w * 32 + l16) * 2048 + quad * 8;

  // Q A-fragments (q-rows mt*16+l16), loop-invariant (32 VGPR)
  bf16x8 qf[2][4];
#pragma unroll
  for (int mt = 0; mt < 2; ++mt)
#pragma unroll
    for (int kk = 0; kk < 4; ++kk)
      qf[mt][kk] = *(const bf16x8*)(qp + (size_t)(mt * 16 + l16) * 128 +
                                    kk * 32 + quad * 8);

  f32x4 oacc[2][2] = {};
  float lsum[2][4] = {};
  const int nkt = (qt >> 1) + 1;

  // prefetch kf for kt=0
  bf16x8 kf[4];
#pragma unroll
  for (int kk = 0; kk < 4; ++kk) kf[kk] = *(const bf16x8*)(kp + kk * 32);

  for (int kt = 0; kt < nkt; ++kt) {
    // V fragments for this iter (used after the barrier -> long natural distance)
    const bf16_t* vro = vp + (size_t)kt * 64;
    bf16x8 vf[2][2];
#pragma unroll
    for (int nd = 0; nd < 2; ++nd)
#pragma unroll
      for (int kkp = 0; kkp < 2; ++kkp)
        vf[nd][kkp] = *(const bf16x8*)(vro + (size_t)nd * 16 * 2048 + kkp * 32);

    // prefetch kf for kt+1 (clamped address: last iter re-loads, no branch)
    const int ktn = (kt + 1 < nkt) ? kt + 1 : kt;
    const bf16_t* kron = kp + (size_t)ktn * 64 * 128;
    bf16x8 kfn[4];
#pragma unroll
    for (int kk = 0; kk < 4; ++kk) kfn[kk] = *(const bf16x8*)(kron + kk * 32);

    // S = Q K^T for this wave's 16 kcols (kf from previous iter's prefetch)
    f32x4 sacc[2] = {};
#pragma unroll
    for (int kk = 0; kk < 4; ++kk)
#pragma unroll
      for (int mt = 0; mt < 2; ++mt)
        sacc[mt] = __builtin_amdgcn_mfma_f32_16x16x32_bf16(qf[mt][kk], kf[kk],
                                                           sacc[mt], 0, 0, 0);
    if (kt == nkt - 1) {  // diagonal tile: mask kcol > qrow
      int kcol = kt * 64 + w * 16 + l16;
#pragma unroll
      for (int mt = 0; mt < 2; ++mt) {
        int qrow = qt * 32 + mt * 16 + quad * 4;
#pragma unroll
        for (int r = 0; r < 4; ++r)
          if (kcol > qrow + r) sacc[mt][r] = -1e30f;
      }
    }

    // fixed-base softmax numerator + P write (C-layout scatter, 8 b16 stores)
    const int pb = kt & 1;
#pragma unroll
    for (int mt = 0; mt < 2; ++mt)
#pragma unroll
      for (int r = 0; r < 4; ++r) {
        float pv = exp2f(sacc[mt][r]);
        lsum[mt][r] += pv;
        Plds[pb][mt * 16 + quad * 4 + r][w * 16 + l16] = (bf16_t)pv;
      }
    __syncthreads();  // the only barrier in the loop

    // O += P * V for this wave's 32-wide d-slice
#pragma unroll
    for (int kkp = 0; kkp < 2; ++kkp) {
      bf16x8 pf[2];
#pragma unroll
      for (int mt = 0; mt < 2; ++mt)
        pf[mt] = *(const bf16x8*)&Plds[pb][mt * 16 + l16][kkp * 32 + quad * 8];
#pragma unroll
      for (int nd = 0; nd < 2; ++nd)
#pragma unroll
        for (int mt = 0; mt < 2; ++mt)
          oacc[mt][nd] = __builtin_amdgcn_mfma_f32_16x16x32_bf16(
              pf[mt], vf[nd][kkp], oacc[mt][nd], 0, 0, 0);
    }

    // rotate prefetch buffer
#pragma unroll
    for (int kk = 0; kk < 4; ++kk) kf[kk] = kfn[kk];
  }

  // row-sum: reduce per-lane partials over the 16-lane group, then over waves
#pragma unroll
  for (int mt = 0; mt < 2; ++mt)
#pragma unroll
    for (int r = 0; r < 4; ++r) {
      float v = lsum[mt][r];
      v += __shfl_xor(v, 1);
      v += __shfl_xor(v, 2);
      v += __shfl_xor(v, 4);
      v += __shfl_xor(v, 8);
      if (l16 == 0) lred[mt * 16 + quad * 4 + r][w] = v;
    }
  __syncthreads();
#pragma unroll
  for (int mt = 0; mt < 2; ++mt)
#pragma unroll
    for (int r = 0; r < 4; ++r) {
      int row = mt * 16 + quad * 4 + r;
      f32x4 t = *(const f32x4*)lred[row];
      float inv = 1.f / (t[0] + t[1] + t[2] + t[3]);
      int pos = qt * 32 + row;
      size_t base = (((size_t)b * 2048 + pos) * 16 + h) * 128;
#pragma unroll
      for (int nd = 0; nd < 2; ++nd)
        ctx[base + w * 32 + nd * 16 + l16] = (bf16_t)(oacc[mt][nd][r] * inv);
    }
}

extern "C" void kernel_launch(void* const* d_in, const int* in_sizes, int n_in,
                              void* d_out, int out_size, void* d_ws, size_t ws_size,
                              hipStream_t stream) {
  (void)in_sizes; (void)n_in; (void)out_size; (void)ws_size;
  const float* x    = (const float*)d_in[0];
  // d_in[1] = mask (causal, structural -> unused)
  const float* cosp = (const float*)d_in[2];
  const float* sinp = (const float*)d_in[3];
  const float* Wq   = (const float*)d_in[4];
  const float* Wk   = (const float*)d_in[5];
  const float* Wv   = (const float*)d_in[6];
  const float* Wo   = (const float*)d_in[7];
  const float* qnw  = (const float*)d_in[8];
  const float* knw  = (const float*)d_in[9];
  float* out = (float*)d_out;

  char* ws = (char*)d_ws;
  bf16_t* qb  = (bf16_t*)(ws);               // 16777216 B
  bf16_t* kb  = (bf16_t*)(ws + 16777216);    //  4194304 B
  bf16_t* vb  = (bf16_t*)(ws + 20971520);    //  4194304 B
  bf16_t* vtb = (bf16_t*)(ws + 25165824);    //  4194304 B
  bf16_t* ctx = (bf16_t*)(ws + 29360128);    // 16777216 B
  bf16_t* xb  = (bf16_t*)(ws + 29360128);    // aliases ctx (dead before attn)
  bf16_t* wqb = (bf16_t*)(ws + 46137344);    //  8388608 B
  bf16_t* wob = (bf16_t*)(ws + 46137344);    // aliases wqb (cast after qkv)
  bf16_t* wkb = (bf16_t*)(ws + 54525952);    //  2097152 B
  bf16_t* wvb = (bf16_t*)(ws + 56623104);    //  2097152 B  (total 58720256 B)

  cast_f32_bf16<<<4096, 256, 0, stream>>>(x, xb);    // 8.39M elems
  cast_f32_bf16<<<2048, 256, 0, stream>>>(Wq, wqb);  // 4.19M
  cast_f32_bf16<<<512, 256, 0, stream>>>(Wk, wkb);   // 1.05M
  cast_f32_bf16<<<512, 256, 0, stream>>>(Wv, wvb);   // 1.05M

  qkv_gemm<<<dim3(24, 32), 256, 0, stream>>>(xb, wqb, wkb, wvb, qb, kb, vb);
  // q scale = HD^-0.5 * log2(e) folded for fixed-base exp2 softmax
  rmsnorm_rope<<<16384, 256, 0, stream>>>(qb, qnw, cosp, sinp, 0.12751742902f);
  rmsnorm_rope<<<4096, 256, 0, stream>>>(kb, knw, cosp, sinp, 1.0f);
  vtrans<<<dim3(32, 2, 8), 256, 0, stream>>>(vb, vtb);
  attn_kernel<<<dim3(64, 16, 2), 256, 0, stream>>>(qb, kb, vtb, ctx);

  cast_f32_bf16<<<2048, 256, 0, stream>>>(Wo, wob);  // wqb dead -> reuse
  out_gemm<<<dim3(16, 32), 256, 0, stream>>>(ctx, wob, out);
}

// Round 8
// 382.497 us; speedup vs baseline: 1.8920x; 1.1542x over previous
//
#include <hip/hip_runtime.h>
#include <hip/hip_bf16.h>

// GroupedQueryAttention: B=2,S=2048,D=2048,H=16,G=4,HD=128, causal, rmsnorm+rope.
// Inputs fp32; OUTPUT fp32. Internal compute bf16 MFMA / fp32 accumulate.
// R8: attn head-merged over the GQA group (4 q-heads share one K/V fetch):
// block = 16 q-rows x 4 heads; 32 MFMA per wave-iter on the same K/V bytes
// (4x arithmetic intensity, half the block-iters); raw v_exp_f32 via
// __builtin_amdgcn_exp2f; XOR-swizzled P buffer (conflict-free b128).
// ws (58.7 MB): qb | kb | vb | vtb | ctx(=xb alias) | wqb(=wob) | wkb | wvb

typedef __bf16 bf16_t;
using bf16x8 = __attribute__((ext_vector_type(8))) __bf16;
using f32x4  = __attribute__((ext_vector_type(4))) float;

#define LDSCP16(gp, lp)                                                       \
  __builtin_amdgcn_global_load_lds(                                           \
      (__attribute__((address_space(1))) void*)(gp),                          \
      (__attribute__((address_space(3))) void*)(lp), 16, 0, 0)

// ---------- fp32 -> bf16 bulk cast (memory-bound) ----------
__global__ __launch_bounds__(256) void cast_f32_bf16(const float* __restrict__ src,
                                                     bf16_t* __restrict__ dst) {
  size_t i = (size_t)blockIdx.x * 256 + threadIdx.x;
  const float* g = src + i * 8;
  f32x4 u0 = *(const f32x4*)g;
  f32x4 u1 = *(const f32x4*)(g + 4);
  bf16x8 v;
  v[0] = (bf16_t)u0[0]; v[1] = (bf16_t)u0[1]; v[2] = (bf16_t)u0[2]; v[3] = (bf16_t)u0[3];
  v[4] = (bf16_t)u1[0]; v[5] = (bf16_t)u1[1]; v[6] = (bf16_t)u1[2]; v[7] = (bf16_t)u1[3];
  *(bf16x8*)(dst + i * 8) = v;
}

// ---------- 128x128-tile GEMM mainloop: C = A[M,K] * B[N,K]^T (both bf16) ----
// global_load_lds w16, source-side XOR chunk swizzle; frag reads 2-way (free).
__device__ __forceinline__ void gemm_tile(const bf16_t* __restrict__ A,
                                          const bf16_t* __restrict__ B, int K,
                                          int m0, int n0, bf16_t* As, bf16_t* Bs,
                                          f32x4 acc[4][4]) {
  const int tid = threadIdx.x;
  const int lane = tid & 63, w = tid >> 6;
  const int quad = lane >> 4, l16 = lane & 15;
  const int wm = (w >> 1) * 64, wn = (w & 1) * 64;
  char* AsB = (char*)As;
  char* BsB = (char*)Bs;
  const int nkt = K >> 6;
  for (int kt = 0; kt < nkt; ++kt) {
#pragma unroll
    for (int i = 0; i < 4; ++i) {
      int s = i * 256 + tid;
      int row = s >> 3, ch = s & 7;
      int sc = ch ^ (row & 7);
      LDSCP16(A + (size_t)(m0 + row) * K + kt * 64 + sc * 8, As + s * 8);
      LDSCP16(B + (size_t)(n0 + row) * K + kt * 64 + sc * 8, Bs + s * 8);
    }
    __syncthreads();
#pragma unroll
    for (int kk = 0; kk < 2; ++kk) {
      bf16x8 af[4], bfv[4];
#pragma unroll
      for (int i = 0; i < 4; ++i) {
        int ra = wm + i * 16 + l16;
        af[i] = *(const bf16x8*)(AsB + ra * 128 + (((kk * 4 + quad) ^ (ra & 7)) << 4));
        int rb = wn + i * 16 + l16;
        bfv[i] = *(const bf16x8*)(BsB + rb * 128 + (((kk * 4 + quad) ^ (rb & 7)) << 4));
      }
#pragma unroll
      for (int im = 0; im < 4; ++im)
#pragma unroll
        for (int in_ = 0; in_ < 4; ++in_)
          acc[im][in_] = __builtin_amdgcn_mfma_f32_16x16x32_bf16(
              af[im], bfv[in_], acc[im][in_], 0, 0, 0);
    }
    __syncthreads();
  }
}

// ---------- fused QKV projection; writes head-major [B,Hn,S,HD] bf16 ----------
__global__ __launch_bounds__(256) void qkv_gemm(
    const bf16_t* __restrict__ x, const bf16_t* __restrict__ Wq,
    const bf16_t* __restrict__ Wk, const bf16_t* __restrict__ Wv,
    bf16_t* __restrict__ qo, bf16_t* __restrict__ ko, bf16_t* __restrict__ vo) {
  __shared__ __align__(16) bf16_t As[128 * 64];
  __shared__ __align__(16) bf16_t Bs[128 * 64];
  const int n0g = blockIdx.x * 128;
  const int m0 = blockIdx.y * 128;
  const bf16_t* B;
  bf16_t* O;
  int Hn, n0;
  if (n0g < 2048)      { B = Wq; O = qo; Hn = 16; n0 = n0g; }
  else if (n0g < 2560) { B = Wk; O = ko; Hn = 4;  n0 = n0g - 2048; }
  else                 { B = Wv; O = vo; Hn = 4;  n0 = n0g - 2560; }
  f32x4 acc[4][4] = {};
  gemm_tile(x, B, 2048, m0, n0, As, Bs, acc);
  const int lane = threadIdx.x & 63, w = threadIdx.x >> 6;
  const int quad = lane >> 4, l16 = lane & 15;
  const int wm = (w >> 1) * 64, wn = (w & 1) * 64;
#pragma unroll
  for (int im = 0; im < 4; ++im)
#pragma unroll
    for (int in_ = 0; in_ < 4; ++in_)
#pragma unroll
      for (int r = 0; r < 4; ++r) {
        int gr = m0 + wm + im * 16 + quad * 4 + r;
        int gc = n0 + wn + in_ * 16 + l16;
        int bb = gr >> 11, ss = gr & 2047, hh = gc >> 7, dd = gc & 127;
        O[(((size_t)bb * Hn + hh) * 2048 + ss) * 128 + dd] = (bf16_t)acc[im][in_][r];
      }
}

// ---------- output projection: out = ctx(bf16) * Wo(bf16)^T, fp32 out --------
__global__ __launch_bounds__(256) void out_gemm(const bf16_t* __restrict__ ctx,
                                                const bf16_t* __restrict__ Wo,
                                                float* __restrict__ out) {
  __shared__ __align__(16) bf16_t As[128 * 64];
  __shared__ __align__(16) bf16_t Bs[128 * 64];
  const int n0 = blockIdx.x * 128, m0 = blockIdx.y * 128;
  f32x4 acc[4][4] = {};
  gemm_tile(ctx, Wo, 2048, m0, n0, As, Bs, acc);
  const int lane = threadIdx.x & 63, w = threadIdx.x >> 6;
  const int quad = lane >> 4, l16 = lane & 15;
  const int wm = (w >> 1) * 64, wn = (w & 1) * 64;
#pragma unroll
  for (int im = 0; im < 4; ++im)
#pragma unroll
    for (int in_ = 0; in_ < 4; ++in_)
#pragma unroll
      for (int r = 0; r < 4; ++r) {
        int gr = m0 + wm + im * 16 + quad * 4 + r;
        int gc = n0 + wn + in_ * 16 + l16;
        out[(size_t)gr * 2048 + gc] = acc[im][in_][r];
      }
}

// ---------- RMSNorm + RoPE (in place on bf16 scratch), one wave per row ------
__global__ __launch_bounds__(256) void rmsnorm_rope(bf16_t* __restrict__ x,
    const float* __restrict__ wgt, const float* __restrict__ cs,
    const float* __restrict__ sn, float outscale) {
  const int row = blockIdx.x * 4 + (threadIdx.x >> 6);
  const int lane = threadIdx.x & 63;
  const int pos = row & 2047;
  bf16_t* p = x + (size_t)row * 128;
  float v1 = (float)p[lane];
  float v2 = (float)p[lane + 64];
  float ss = v1 * v1 + v2 * v2;
#pragma unroll
  for (int m = 32; m; m >>= 1) ss += __shfl_xor(ss, m);
  float rr = rsqrtf(ss * (1.0f / 128.0f) + 1e-6f);
  float n1 = v1 * rr * wgt[lane];
  float n2 = v2 * rr * wgt[lane + 64];
  float c1 = cs[pos * 128 + lane],      s1 = sn[pos * 128 + lane];
  float c2 = cs[pos * 128 + lane + 64], s2 = sn[pos * 128 + lane + 64];
  p[lane]      = (bf16_t)((n1 * c1 - n2 * s1) * outscale);
  p[lane + 64] = (bf16_t)((n2 * c2 + n1 * s2) * outscale);
}

// ---------- V transpose: [BG,S,HD] -> [BG,HD,S] ----------
__global__ __launch_bounds__(256) void vtrans(const bf16_t* __restrict__ v,
                                              bf16_t* __restrict__ vt) {
  __shared__ bf16_t t[64][72];
  const int bg = blockIdx.z, t0 = blockIdx.x * 64, d0 = blockIdx.y * 64;
  const int tid = threadIdx.x;
  const int r = tid >> 3, c = (tid & 7) * 8;
  const bf16_t* src = v + ((size_t)bg * 2048 + t0) * 128 + d0;
#pragma unroll
  for (int it = 0; it < 2; ++it) {
    uint4 val = *(const uint4*)(src + (size_t)(r + it * 32) * 128 + c);
    *(uint4*)&t[r + it * 32][c] = val;
  }
  __syncthreads();
#pragma unroll
  for (int it = 0; it < 2; ++it) {
    int d = r + it * 32;
    bf16_t tmp[8];
#pragma unroll
    for (int j = 0; j < 8; ++j) tmp[j] = t[c + j][d];
    *(uint4*)(vt + ((size_t)bg * 128 + d0 + d) * 2048 + t0 + c) = *(uint4*)tmp;
  }
}

// ---------- flash attention, GQA head-merged ----------
// Block = (qi, g, b): 16 q-rows x 4 heads of group g; K-loop in 64-col tiles.
// QK: wave w owns kcols [16w,+16) -> one K fetch serves 4 heads (16 MFMA).
// PV: wave w owns d-slice [32w,+32) -> one V fetch serves 4 heads (16 MFMA).
// P: 4 x (16x64) XOR-swizzled ping-pong LDS; ONE barrier/iter. Fixed-base
// softmax (HD^-0.5*log2e folded into q), raw v_exp_f32.
__global__ __launch_bounds__(256) void attn_kernel(const bf16_t* __restrict__ q,
    const bf16_t* __restrict__ k, const bf16_t* __restrict__ vt,
    bf16_t* __restrict__ ctx) {
  __shared__ __align__(16) char Plds[2][4][2048];  // [pb][h][16 rows x 128B]
  __shared__ __align__(16) float lred[4][16][4];
  const int qi = blockIdx.x, g = blockIdx.y, b = blockIdx.z;
  const int qt = ((b ^ g) & 1) ? 127 - qi : qi;  // balance remap (16-row tiles)
  const int tid = threadIdx.x, w = tid >> 6, lane = tid & 63;
  const int quad = lane >> 4, l16 = lane & 15;
  const bf16_t* kp = k + ((size_t)b * 4 + g) * 2048 * 128 +
                     (size_t)(w * 16 + l16) * 128 + quad * 8;
  const bf16_t* vp = vt + ((size_t)b * 4 + g) * 128 * 2048 +
                     (size_t)(w * 32 + l16) * 2048 + quad * 8;

  // Q A-fragments: 16 rows (m=l16) per head, loop-invariant (64 VGPR)
  bf16x8 qf[4][4];
#pragma unroll
  for (int h = 0; h < 4; ++h)
#pragma unroll
    for (int kk = 0; kk < 4; ++kk)
      qf[h][kk] = *(const bf16x8*)(q +
          (((size_t)b * 16 + g * 4 + h) * 2048 + (size_t)qt * 16 + l16) * 128 +
          kk * 32 + quad * 8);

  f32x4 oacc[4][2] = {};
  float lsum[4][4] = {};
  const int nkt = (qt >> 2) + 1;
  for (int kt = 0; kt < nkt; ++kt) {
    // K fragments (B-layout n=l16 -> kcol w*16+l16), one fetch for 4 heads
    const bf16_t* kro = kp + (size_t)kt * 64 * 128;
    bf16x8 kf[4];
#pragma unroll
    for (int kk = 0; kk < 4; ++kk) kf[kk] = *(const bf16x8*)(kro + kk * 32);
    // V fragments (B-layout n=l16 -> d = w*32+nd*16+l16), used after barrier
    const bf16_t* vro = vp + (size_t)kt * 64;
    bf16x8 vf[2][2];
#pragma unroll
    for (int nd = 0; nd < 2; ++nd)
#pragma unroll
      for (int kkp = 0; kkp < 2; ++kkp)
        vf[nd][kkp] = *(const bf16x8*)(vro + (size_t)nd * 16 * 2048 + kkp * 32);

    // S = Q K^T for 4 heads on this wave's 16 kcols
    f32x4 sacc[4] = {};
#pragma unroll
    for (int kk = 0; kk < 4; ++kk)
#pragma unroll
      for (int h = 0; h < 4; ++h)
        sacc[h] = __builtin_amdgcn_mfma_f32_16x16x32_bf16(qf[h][kk], kf[kk],
                                                          sacc[h], 0, 0, 0);
    if (kt == nkt - 1) {  // diagonal tile: mask kcol > qrow (head-independent)
      int kcol = kt * 64 + w * 16 + l16;
      int qrow = qt * 16 + quad * 4;
#pragma unroll
      for (int r = 0; r < 4; ++r)
        if (kcol > qrow + r)
#pragma unroll
          for (int h = 0; h < 4; ++h) sacc[h][r] = -1e30f;
    }

    // softmax numerator (raw v_exp_f32) + swizzled P write
    const int pb = kt & 1;
#pragma unroll
    for (int h = 0; h < 4; ++h)
#pragma unroll
      for (int r = 0; r < 4; ++r) {
        float pv = __builtin_amdgcn_exp2f(sacc[h][r]);
        lsum[h][r] += pv;
        int row = quad * 4 + r;
        int c = w * 2 + (l16 >> 3);
        *(bf16_t*)(Plds[pb][h] + row * 128 + ((c ^ (row & 7)) << 4) +
                   ((l16 & 7) << 1)) = (bf16_t)pv;
      }
    __syncthreads();  // the only barrier in the loop

    // O += P * V for 4 heads on this wave's 32-wide d-slice
#pragma unroll
    for (int kkp = 0; kkp < 2; ++kkp) {
      bf16x8 pf[4];
#pragma unroll
      for (int h = 0; h < 4; ++h)
        pf[h] = *(const bf16x8*)(Plds[pb][h] + l16 * 128 +
                                 (((kkp * 4 + quad) ^ (l16 & 7)) << 4));
#pragma unroll
      for (int nd = 0; nd < 2; ++nd)
#pragma unroll
        for (int h = 0; h < 4; ++h)
          oacc[h][nd] = __builtin_amdgcn_mfma_f32_16x16x32_bf16(
              pf[h], vf[nd][kkp], oacc[h][nd], 0, 0, 0);
    }
  }

  // row-sum: reduce per-lane partials (16 kcols) then across waves
#pragma unroll
  for (int h = 0; h < 4; ++h)
#pragma unroll
    for (int r = 0; r < 4; ++r) {
      float v = lsum[h][r];
      v += __shfl_xor(v, 1);
      v += __shfl_xor(v, 2);
      v += __shfl_xor(v, 4);
      v += __shfl_xor(v, 8);
      if (l16 == 0) lred[h][quad * 4 + r][w] = v;
    }
  __syncthreads();
#pragma unroll
  for (int h = 0; h < 4; ++h)
#pragma unroll
    for (int r = 0; r < 4; ++r) {
      int row = quad * 4 + r;
      f32x4 t = *(const f32x4*)lred[h][row];
      float inv = 1.f / (t[0] + t[1] + t[2] + t[3]);
      int pos = qt * 16 + row;
      size_t base = (((size_t)b * 2048 + pos) * 16 + g * 4 + h) * 128;
#pragma unroll
      for (int nd = 0; nd < 2; ++nd)
        ctx[base + w * 32 + nd * 16 + l16] = (bf16_t)(oacc[h][nd][r] * inv);
    }
}

extern "C" void kernel_launch(void* const* d_in, const int* in_sizes, int n_in,
                              void* d_out, int out_size, void* d_ws, size_t ws_size,
                              hipStream_t stream) {
  (void)in_sizes; (void)n_in; (void)out_size; (void)ws_size;
  const float* x    = (const float*)d_in[0];
  const float* cosp = (const float*)d_in[2];
  const float* sinp = (const float*)d_in[3];
  const float* Wq   = (const float*)d_in[4];
  const float* Wk   = (const float*)d_in[5];
  const float* Wv   = (const float*)d_in[6];
  const float* Wo   = (const float*)d_in[7];
  const float* qnw  = (const float*)d_in[8];
  const float* knw  = (const float*)d_in[9];
  float* out = (float*)d_out;

  char* ws = (char*)d_ws;
  bf16_t* qb  = (bf16_t*)(ws);               // 16777216 B
  bf16_t* kb  = (bf16_t*)(ws + 16777216);    //  4194304 B
  bf16_t* vb  = (bf16_t*)(ws + 20971520);    //  4194304 B
  bf16_t* vtb = (bf16_t*)(ws + 25165824);    //  4194304 B
  bf16_t* ctx = (bf16_t*)(ws + 29360128);    // 16777216 B
  bf16_t* xb  = (bf16_t*)(ws + 29360128);    // aliases ctx (dead before attn)
  bf16_t* wqb = (bf16_t*)(ws + 46137344);    //  8388608 B
  bf16_t* wob = (bf16_t*)(ws + 46137344);    // aliases wqb (cast after qkv)
  bf16_t* wkb = (bf16_t*)(ws + 54525952);    //  2097152 B
  bf16_t* wvb = (bf16_t*)(ws + 56623104);    //  2097152 B

  cast_f32_bf16<<<4096, 256, 0, stream>>>(x, xb);
  cast_f32_bf16<<<2048, 256, 0, stream>>>(Wq, wqb);
  cast_f32_bf16<<<512, 256, 0, stream>>>(Wk, wkb);
  cast_f32_bf16<<<512, 256, 0, stream>>>(Wv, wvb);

  qkv_gemm<<<dim3(24, 32), 256, 0, stream>>>(xb, wqb, wkb, wvb, qb, kb, vb);
  // q scale = HD^-0.5 * log2(e) folded for fixed-base exp2 softmax
  rmsnorm_rope<<<16384, 256, 0, stream>>>(qb, qnw, cosp, sinp, 0.12751742902f);
  rmsnorm_rope<<<4096, 256, 0, stream>>>(kb, knw, cosp, sinp, 1.0f);
  vtrans<<<dim3(32, 2, 8), 256, 0, stream>>>(vb, vtb);
  attn_kernel<<<dim3(128, 4, 2), 256, 0, stream>>>(qb, kb, vtb, ctx);

  cast_f32_bf16<<<2048, 256, 0, stream>>>(Wo, wob);
  out_gemm<<<dim3(16, 32), 256, 0, stream>>>(ctx, wob, out);
}

// Round 9
// 344.523 us; speedup vs baseline: 2.1005x; 1.1102x over previous
//
#include <hip/hip_runtime.h>
#include <hip/hip_bf16.h>

// GroupedQueryAttention: B=2,S=2048,D=2048,H=16,G=4,HD=128, causal, rmsnorm+rope.
// Inputs fp32; OUTPUT fp32. Internal compute bf16 MFMA / fp32 accumulate.
// R9: attn uniform-length blocks (each does q-tiles {qi,127-qi} -> 33 iters flat),
// transposed QK (S^T via operand swap) -> packed bf16x4 P-writes + scalar lsum;
// kernel count 11->7 (merged casts, merged rmsnorms).
// ws (58.7 MB): qb | kb | vb | vtb | ctx(=xb alias) | wqb(=wob) | wkb | wvb

typedef __bf16 bf16_t;
using bf16x4 = __attribute__((ext_vector_type(4))) __bf16;
using bf16x8 = __attribute__((ext_vector_type(8))) __bf16;
using f32x4  = __attribute__((ext_vector_type(4))) float;

#define LDSCP16(gp, lp)                                                       \
  __builtin_amdgcn_global_load_lds(                                           \
      (__attribute__((address_space(1))) void*)(gp),                          \
      (__attribute__((address_space(3))) void*)(lp), 16, 0, 0)

// ---------- merged fp32 -> bf16 casts: x | Wq | Wk | Wv ----------
__global__ __launch_bounds__(256) void cast_all(
    const float* __restrict__ x, const float* __restrict__ wq,
    const float* __restrict__ wk, const float* __restrict__ wv,
    bf16_t* __restrict__ xb, bf16_t* __restrict__ wqb,
    bf16_t* __restrict__ wkb, bf16_t* __restrict__ wvb) {
  int blk = blockIdx.x;
  const float* s;
  bf16_t* d;
  size_t base;
  if (blk < 4096)      { s = x;  d = xb;  base = blk; }
  else if (blk < 6144) { s = wq; d = wqb; base = blk - 4096; }
  else if (blk < 6656) { s = wk; d = wkb; base = blk - 6144; }
  else                 { s = wv; d = wvb; base = blk - 6656; }
  size_t i = base * 256 + threadIdx.x;
  const float* g = s + i * 8;
  f32x4 u0 = *(const f32x4*)g;
  f32x4 u1 = *(const f32x4*)(g + 4);
  bf16x8 v;
  v[0] = (bf16_t)u0[0]; v[1] = (bf16_t)u0[1]; v[2] = (bf16_t)u0[2]; v[3] = (bf16_t)u0[3];
  v[4] = (bf16_t)u1[0]; v[5] = (bf16_t)u1[1]; v[6] = (bf16_t)u1[2]; v[7] = (bf16_t)u1[3];
  *(bf16x8*)(d + i * 8) = v;
}

// ---------- single fp32 -> bf16 cast (Wo, after qkv frees wqb) ----------
__global__ __launch_bounds__(256) void cast_f32_bf16(const float* __restrict__ src,
                                                     bf16_t* __restrict__ dst) {
  size_t i = (size_t)blockIdx.x * 256 + threadIdx.x;
  const float* g = src + i * 8;
  f32x4 u0 = *(const f32x4*)g;
  f32x4 u1 = *(const f32x4*)(g + 4);
  bf16x8 v;
  v[0] = (bf16_t)u0[0]; v[1] = (bf16_t)u0[1]; v[2] = (bf16_t)u0[2]; v[3] = (bf16_t)u0[3];
  v[4] = (bf16_t)u1[0]; v[5] = (bf16_t)u1[1]; v[6] = (bf16_t)u1[2]; v[7] = (bf16_t)u1[3];
  *(bf16x8*)(dst + i * 8) = v;
}

// ---------- 128x128-tile GEMM mainloop: C = A[M,K] * B[N,K]^T (both bf16) ----
// global_load_lds w16, source-side XOR chunk swizzle; frag reads 2-way (free).
__device__ __forceinline__ void gemm_tile(const bf16_t* __restrict__ A,
                                          const bf16_t* __restrict__ B, int K,
                                          int m0, int n0, bf16_t* As, bf16_t* Bs,
                                          f32x4 acc[4][4]) {
  const int tid = threadIdx.x;
  const int lane = tid & 63, w = tid >> 6;
  const int quad = lane >> 4, l16 = lane & 15;
  const int wm = (w >> 1) * 64, wn = (w & 1) * 64;
  char* AsB = (char*)As;
  char* BsB = (char*)Bs;
  const int nkt = K >> 6;
  for (int kt = 0; kt < nkt; ++kt) {
#pragma unroll
    for (int i = 0; i < 4; ++i) {
      int s = i * 256 + tid;
      int row = s >> 3, ch = s & 7;
      int sc = ch ^ (row & 7);
      LDSCP16(A + (size_t)(m0 + row) * K + kt * 64 + sc * 8, As + s * 8);
      LDSCP16(B + (size_t)(n0 + row) * K + kt * 64 + sc * 8, Bs + s * 8);
    }
    __syncthreads();
#pragma unroll
    for (int kk = 0; kk < 2; ++kk) {
      bf16x8 af[4], bfv[4];
#pragma unroll
      for (int i = 0; i < 4; ++i) {
        int ra = wm + i * 16 + l16;
        af[i] = *(const bf16x8*)(AsB + ra * 128 + (((kk * 4 + quad) ^ (ra & 7)) << 4));
        int rb = wn + i * 16 + l16;
        bfv[i] = *(const bf16x8*)(BsB + rb * 128 + (((kk * 4 + quad) ^ (rb & 7)) << 4));
      }
#pragma unroll
      for (int im = 0; im < 4; ++im)
#pragma unroll
        for (int in_ = 0; in_ < 4; ++in_)
          acc[im][in_] = __builtin_amdgcn_mfma_f32_16x16x32_bf16(
              af[im], bfv[in_], acc[im][in_], 0, 0, 0);
    }
    __syncthreads();
  }
}

// ---------- fused QKV projection; writes head-major [B,Hn,S,HD] bf16 ----------
__global__ __launch_bounds__(256) void qkv_gemm(
    const bf16_t* __restrict__ x, const bf16_t* __restrict__ Wq,
    const bf16_t* __restrict__ Wk, const bf16_t* __restrict__ Wv,
    bf16_t* __restrict__ qo, bf16_t* __restrict__ ko, bf16_t* __restrict__ vo) {
  __shared__ __align__(16) bf16_t As[128 * 64];
  __shared__ __align__(16) bf16_t Bs[128 * 64];
  const int n0g = blockIdx.x * 128;
  const int m0 = blockIdx.y * 128;
  const bf16_t* B;
  bf16_t* O;
  int Hn, n0;
  if (n0g < 2048)      { B = Wq; O = qo; Hn = 16; n0 = n0g; }
  else if (n0g < 2560) { B = Wk; O = ko; Hn = 4;  n0 = n0g - 2048; }
  else                 { B = Wv; O = vo; Hn = 4;  n0 = n0g - 2560; }
  f32x4 acc[4][4] = {};
  gemm_tile(x, B, 2048, m0, n0, As, Bs, acc);
  const int lane = threadIdx.x & 63, w = threadIdx.x >> 6;
  const int quad = lane >> 4, l16 = lane & 15;
  const int wm = (w >> 1) * 64, wn = (w & 1) * 64;
#pragma unroll
  for (int im = 0; im < 4; ++im)
#pragma unroll
    for (int in_ = 0; in_ < 4; ++in_)
#pragma unroll
      for (int r = 0; r < 4; ++r) {
        int gr = m0 + wm + im * 16 + quad * 4 + r;
        int gc = n0 + wn + in_ * 16 + l16;
        int bb = gr >> 11, ss = gr & 2047, hh = gc >> 7, dd = gc & 127;
        O[(((size_t)bb * Hn + hh) * 2048 + ss) * 128 + dd] = (bf16_t)acc[im][in_][r];
      }
}

// ---------- output projection: out = ctx(bf16) * Wo(bf16)^T, fp32 out --------
__global__ __launch_bounds__(256) void out_gemm(const bf16_t* __restrict__ ctx,
                                                const bf16_t* __restrict__ Wo,
                                                float* __restrict__ out) {
  __shared__ __align__(16) bf16_t As[128 * 64];
  __shared__ __align__(16) bf16_t Bs[128 * 64];
  const int n0 = blockIdx.x * 128, m0 = blockIdx.y * 128;
  f32x4 acc[4][4] = {};
  gemm_tile(ctx, Wo, 2048, m0, n0, As, Bs, acc);
  const int lane = threadIdx.x & 63, w = threadIdx.x >> 6;
  const int quad = lane >> 4, l16 = lane & 15;
  const int wm = (w >> 1) * 64, wn = (w & 1) * 64;
#pragma unroll
  for (int im = 0; im < 4; ++im)
#pragma unroll
    for (int in_ = 0; in_ < 4; ++in_)
#pragma unroll
      for (int r = 0; r < 4; ++r) {
        int gr = m0 + wm + im * 16 + quad * 4 + r;
        int gc = n0 + wn + in_ * 16 + l16;
        out[(size_t)gr * 2048 + gc] = acc[im][in_][r];
      }
}

// ---------- merged RMSNorm + RoPE for q and k (in place), one wave per row ----
__global__ __launch_bounds__(256) void rmsnorm_rope_all(
    bf16_t* __restrict__ qx, bf16_t* __restrict__ kx,
    const float* __restrict__ qw, const float* __restrict__ kw,
    const float* __restrict__ cs, const float* __restrict__ sn, float qscale) {
  int blk = blockIdx.x;
  bf16_t* basep;
  const float* wgt;
  float outscale;
  int row;
  if (blk < 16384) { basep = qx; wgt = qw; outscale = qscale; row = blk * 4 + (threadIdx.x >> 6); }
  else { basep = kx; wgt = kw; outscale = 1.0f; row = (blk - 16384) * 4 + (threadIdx.x >> 6); }
  const int lane = threadIdx.x & 63;
  const int pos = row & 2047;
  bf16_t* p = basep + (size_t)row * 128;
  float v1 = (float)p[lane];
  float v2 = (float)p[lane + 64];
  float ss = v1 * v1 + v2 * v2;
#pragma unroll
  for (int m = 32; m; m >>= 1) ss += __shfl_xor(ss, m);
  float rr = rsqrtf(ss * (1.0f / 128.0f) + 1e-6f);
  float n1 = v1 * rr * wgt[lane];
  float n2 = v2 * rr * wgt[lane + 64];
  float c1 = cs[pos * 128 + lane],      s1 = sn[pos * 128 + lane];
  float c2 = cs[pos * 128 + lane + 64], s2 = sn[pos * 128 + lane + 64];
  p[lane]      = (bf16_t)((n1 * c1 - n2 * s1) * outscale);
  p[lane + 64] = (bf16_t)((n2 * c2 + n1 * s2) * outscale);
}

// ---------- V transpose: [BG,S,HD] -> [BG,HD,S] ----------
__global__ __launch_bounds__(256) void vtrans(const bf16_t* __restrict__ v,
                                              bf16_t* __restrict__ vt) {
  __shared__ bf16_t t[64][72];
  const int bg = blockIdx.z, t0 = blockIdx.x * 64, d0 = blockIdx.y * 64;
  const int tid = threadIdx.x;
  const int r = tid >> 3, c = (tid & 7) * 8;
  const bf16_t* src = v + ((size_t)bg * 2048 + t0) * 128 + d0;
#pragma unroll
  for (int it = 0; it < 2; ++it) {
    uint4 val = *(const uint4*)(src + (size_t)(r + it * 32) * 128 + c);
    *(uint4*)&t[r + it * 32][c] = val;
  }
  __syncthreads();
#pragma unroll
  for (int it = 0; it < 2; ++it) {
    int d = r + it * 32;
    bf16_t tmp[8];
#pragma unroll
    for (int j = 0; j < 8; ++j) tmp[j] = t[c + j][d];
    *(uint4*)(vt + ((size_t)bg * 128 + d0 + d) * 2048 + t0 + c) = *(uint4*)tmp;
  }
}

// ---------- flash attention: GQA head-merged, uniform blocks, transposed QK --
// Block (qi,g,b) processes q-tiles {qi, 127-qi}: nkt sums to 33 for every block
// -> 512 identical-duration blocks, 2/CU, no tail. Per tile: 16 q-rows x 4
// heads; K-loop in 64-col tiles. S^T = K*Q^T (operand swap) puts a lane's 4
// values on 4 consecutive kcols of one q-row -> one packed bf16x4 8B P-write
// per head and a scalar lsum per head. P: XOR-swizzled ping-pong LDS, one
// barrier/iter. Fixed-base softmax (HD^-0.5*log2e folded into q scale).
__global__ __launch_bounds__(256) void attn_kernel(const bf16_t* __restrict__ q,
    const bf16_t* __restrict__ k, const bf16_t* __restrict__ vt,
    bf16_t* __restrict__ ctx) {
  __shared__ __align__(16) char Plds[2][4][2048];  // [pb][h][16 rows x 128B]
  __shared__ __align__(16) float lred[4][16][4];
  const int qi = blockIdx.x, g = blockIdx.y, b = blockIdx.z;
  const int tid = threadIdx.x, w = tid >> 6, lane = tid & 63;
  const int quad = lane >> 4, l16 = lane & 15;
  const bf16_t* kp = k + ((size_t)b * 4 + g) * 2048 * 128 +
                     (size_t)(w * 16 + l16) * 128 + quad * 8;
  const bf16_t* vp = vt + ((size_t)b * 4 + g) * 128 * 2048 +
                     (size_t)(w * 32 + l16) * 2048 + quad * 8;

#pragma unroll 1
  for (int ph = 0; ph < 2; ++ph) {
    const int qt = ph ? 127 - qi : qi;

    // Q A-fragments: 16 rows (m=l16) per head (64 VGPR)
    bf16x8 qf[4][4];
#pragma unroll
    for (int h = 0; h < 4; ++h)
#pragma unroll
      for (int kk = 0; kk < 4; ++kk)
        qf[h][kk] = *(const bf16x8*)(q +
            (((size_t)b * 16 + g * 4 + h) * 2048 + (size_t)qt * 16 + l16) * 128 +
            kk * 32 + quad * 8);

    f32x4 oacc[4][2] = {};
    float lsum[4] = {};
    const int nkt = (qt >> 2) + 1;
    for (int kt = 0; kt < nkt; ++kt) {
      // K fragments (A-operand of S^T: m = kcol w*16+l16), one fetch, 4 heads
      const bf16_t* kro = kp + (size_t)kt * 64 * 128;
      bf16x8 kf[4];
#pragma unroll
      for (int kk = 0; kk < 4; ++kk) kf[kk] = *(const bf16x8*)(kro + kk * 32);
      // V fragments (B-layout n=l16 -> d = w*32+nd*16+l16), used after barrier
      const bf16_t* vro = vp + (size_t)kt * 64;
      bf16x8 vf[2][2];
#pragma unroll
      for (int nd = 0; nd < 2; ++nd)
#pragma unroll
        for (int kkp = 0; kkp < 2; ++kkp)
          vf[nd][kkp] = *(const bf16x8*)(vro + (size_t)nd * 16 * 2048 + kkp * 32);

      // S^T = K Q^T: C row = kcol_local (quad*4+r), col = qrow_local (l16)
      f32x4 sacc[4] = {};
#pragma unroll
      for (int kk = 0; kk < 4; ++kk)
#pragma unroll
        for (int h = 0; h < 4; ++h)
          sacc[h] = __builtin_amdgcn_mfma_f32_16x16x32_bf16(kf[kk], qf[h][kk],
                                                            sacc[h], 0, 0, 0);
      if (kt == nkt - 1) {  // diagonal tile: mask kcol > qrow
        int kcol = kt * 64 + w * 16 + quad * 4;
        int qrow = qt * 16 + l16;
#pragma unroll
        for (int r = 0; r < 4; ++r)
          if (kcol + r > qrow)
#pragma unroll
            for (int h = 0; h < 4; ++h) sacc[h][r] = -1e30f;
      }

      // softmax numerator + packed 8B P-write (row = qrow l16, 4 consec kcols)
      const int pb = kt & 1;
      const int c0 = w * 2 + (quad >> 1);
      const int woff = l16 * 128 + ((c0 ^ (l16 & 7)) << 4) + ((quad & 1) << 3);
#pragma unroll
      for (int h = 0; h < 4; ++h) {
        float p0 = __builtin_amdgcn_exp2f(sacc[h][0]);
        float p1 = __builtin_amdgcn_exp2f(sacc[h][1]);
        float p2 = __builtin_amdgcn_exp2f(sacc[h][2]);
        float p3 = __builtin_amdgcn_exp2f(sacc[h][3]);
        lsum[h] += (p0 + p1) + (p2 + p3);
        bf16x4 pk;
        pk[0] = (bf16_t)p0; pk[1] = (bf16_t)p1; pk[2] = (bf16_t)p2; pk[3] = (bf16_t)p3;
        *(bf16x4*)(Plds[pb][h] + woff) = pk;
      }
      __syncthreads();  // the only barrier in the loop

      // O += P * V: A = P (m=qrow l16, k=kcol quad*8+j), B = V^T
#pragma unroll
      for (int kkp = 0; kkp < 2; ++kkp) {
        bf16x8 pf[4];
#pragma unroll
        for (int h = 0; h < 4; ++h)
          pf[h] = *(const bf16x8*)(Plds[pb][h] + l16 * 128 +
                                   (((kkp * 4 + quad) ^ (l16 & 7)) << 4));
#pragma unroll
        for (int nd = 0; nd < 2; ++nd)
#pragma unroll
          for (int h = 0; h < 4; ++h)
            oacc[h][nd] = __builtin_amdgcn_mfma_f32_16x16x32_bf16(
                pf[h], vf[nd][kkp], oacc[h][nd], 0, 0, 0);
      }
    }

    // row-sum: lane's lsum covers its 4 kcols at qrow=l16; reduce across quads
    // (lanes l16, l16+16, l16+32, l16+48) then across waves via LDS.
#pragma unroll
    for (int h = 0; h < 4; ++h) {
      float v = lsum[h];
      v += __shfl_xor(v, 16);
      v += __shfl_xor(v, 32);
      if (quad == 0) lred[h][l16][w] = v;
    }
    __syncthreads();
    // epilogue: oacc C-layout row = qrow_local quad*4+r, col = d_local l16
#pragma unroll
    for (int h = 0; h < 4; ++h)
#pragma unroll
      for (int r = 0; r < 4; ++r) {
        int row = quad * 4 + r;
        f32x4 t = *(const f32x4*)lred[h][row];
        float inv = 1.f / (t[0] + t[1] + t[2] + t[3]);
        int pos = qt * 16 + row;
        size_t base = (((size_t)b * 2048 + pos) * 16 + g * 4 + h) * 128;
#pragma unroll
        for (int nd = 0; nd < 2; ++nd)
          ctx[base + w * 32 + nd * 16 + l16] = (bf16_t)(oacc[h][nd][r] * inv);
      }
  }
}

extern "C" void kernel_launch(void* const* d_in, const int* in_sizes, int n_in,
                              void* d_out, int out_size, void* d_ws, size_t ws_size,
                              hipStream_t stream) {
  (void)in_sizes; (void)n_in; (void)out_size; (void)ws_size;
  const float* x    = (const float*)d_in[0];
  const float* cosp = (const float*)d_in[2];
  const float* sinp = (const float*)d_in[3];
  const float* Wq   = (const float*)d_in[4];
  const float* Wk   = (const float*)d_in[5];
  const float* Wv   = (const float*)d_in[6];
  const float* Wo   = (const float*)d_in[7];
  const float* qnw  = (const float*)d_in[8];
  const float* knw  = (const float*)d_in[9];
  float* out = (float*)d_out;

  char* ws = (char*)d_ws;
  bf16_t* qb  = (bf16_t*)(ws);               // 16777216 B
  bf16_t* kb  = (bf16_t*)(ws + 16777216);    //  4194304 B
  bf16_t* vb  = (bf16_t*)(ws + 20971520);    //  4194304 B
  bf16_t* vtb = (bf16_t*)(ws + 25165824);    //  4194304 B
  bf16_t* ctx = (bf16_t*)(ws + 29360128);    // 16777216 B
  bf16_t* xb  = (bf16_t*)(ws + 29360128);    // aliases ctx (dead before attn)
  bf16_t* wqb = (bf16_t*)(ws + 46137344);    //  8388608 B
  bf16_t* wob = (bf16_t*)(ws + 46137344);    // aliases wqb (cast after qkv)
  bf16_t* wkb = (bf16_t*)(ws + 54525952);    //  2097152 B
  bf16_t* wvb = (bf16_t*)(ws + 56623104);    //  2097152 B

  cast_all<<<7168, 256, 0, stream>>>(x, Wq, Wk, Wv, xb, wqb, wkb, wvb);
  qkv_gemm<<<dim3(24, 32), 256, 0, stream>>>(xb, wqb, wkb, wvb, qb, kb, vb);
  // q scale = HD^-0.5 * log2(e) folded for fixed-base exp2 softmax
  rmsnorm_rope_all<<<20480, 256, 0, stream>>>(qb, kb, qnw, knw, cosp, sinp,
                                              0.12751742902f);
  vtrans<<<dim3(32, 2, 8), 256, 0, stream>>>(vb, vtb);
  attn_kernel<<<dim3(64, 4, 2), 256, 0, stream>>>(qb, kb, vtb, ctx);
  cast_f32_bf16<<<2048, 256, 0, stream>>>(Wo, wob);
  out_gemm<<<dim3(16, 32), 256, 0, stream>>>(ctx, wob, out);
}